// Round 11
// baseline (449.418 us; speedup 1.0000x reference)
//
#include <hip/hip_runtime.h>
#include <hip/hip_bf16.h>

// Attention with softmax over the QUERY axis (axis=1):
//   attn[:,q,k] = exp(S[q,k]) / Z[k],  Z[k] = sum_q exp(S[q,k])
//   out = expS @ (diag(1/Z) V)   -- 1/Z folded into V by k_zv's epilogue.
// B=2, N=8192, D=256. All matmuls via mfma_f32_16x16x32_bf16.
// R11: k_attn restructured: V read from global (L1/L2-resident, no staging),
// P double-buffered with DEFERRED PV -> ONE barrier per k-tile; S(kt) and
// PV(kt-1) share one scheduling region so their MFMAs interleave.
// LDS 80KB (K dbuf 2x32K + P dbuf 2x8K).

#define N_ 8192
#define SCALE 0.0625f

typedef __attribute__((ext_vector_type(8))) short short8;
typedef __attribute__((ext_vector_type(4))) float f32x4;
typedef __attribute__((ext_vector_type(4))) unsigned short ushort4_t;

__device__ inline unsigned short f2bf(float f) {
    unsigned int x = __float_as_uint(f);
    unsigned int r = (x + 0x7fffu + ((x >> 16) & 1u)) >> 16;  // RNE
    return (unsigned short)r;
}

__device__ inline short8 ldg8(const unsigned short* p) {
    return *reinterpret_cast<const short8*>(p);
}

__device__ inline short8 cvt8(const float* p) {
    float4 a = *(const float4*)p;
    float4 b = *(const float4*)(p + 4);
    short8 r;
    r[0] = (short)f2bf(a.x); r[1] = (short)f2bf(a.y);
    r[2] = (short)f2bf(a.z); r[3] = (short)f2bf(a.w);
    r[4] = (short)f2bf(b.x); r[5] = (short)f2bf(b.y);
    r[6] = (short)f2bf(b.z); r[7] = (short)f2bf(b.w);
    return r;
}

__device__ inline f32x4 mfma16(short8 a, short8 b, f32x4 c) {
    return __builtin_amdgcn_mfma_f32_16x16x32_bf16(a, b, c, 0, 0, 0);
}

__device__ inline float bf2f(unsigned short u) {
    return __uint_as_float(((unsigned)u) << 16);
}

#define PIN8(v) asm volatile("" : "+v"(v))

typedef __attribute__((address_space(3))) unsigned int lds_u32;
typedef __attribute__((address_space(1))) const unsigned int glb_u32;
__device__ __forceinline__ void gll16(const void* g, void* l) {
    __builtin_amdgcn_global_load_lds((glb_u32*)g, (lds_u32*)l, 16, 0, 0);
}
#define WAIT_VM0()   asm volatile("s_waitcnt vmcnt(0)" ::: "memory")
#define WAIT_LGKM0() asm volatile("s_waitcnt lgkmcnt(0)" ::: "memory")
#define BARRIER()    __builtin_amdgcn_s_barrier()

// ---------------------------------------------------------------------------
// Kernel 0: W (3 x 256x256 f32) -> Wb (768x256 bf16), concatenated Q|K|V.
// ---------------------------------------------------------------------------
__global__ __launch_bounds__(256) void k_cvtw(
    const float* __restrict__ Wq, const float* __restrict__ Wk,
    const float* __restrict__ Wv, unsigned short* __restrict__ Wb)
{
    int t = blockIdx.x * 256 + threadIdx.x;
    int e8 = t * 8;
    const float* src = (e8 < 65536) ? Wq + e8
                     : (e8 < 131072) ? Wk + (e8 - 65536)
                                     : Wv + (e8 - 131072);
    *reinterpret_cast<short8*>(Wb + e8) = cvt8(src);
}

// ---------------------------------------------------------------------------
// Kernel 1: QKV projection, x read ONCE (proven R5).
// ---------------------------------------------------------------------------
__global__ __launch_bounds__(512) void k_proj(
    const float* __restrict__ x, const unsigned short* __restrict__ Wb,
    unsigned short* __restrict__ Qb, unsigned short* __restrict__ Kb,
    unsigned short* __restrict__ Vt)
{
    __shared__ unsigned short sX[64 * 256];   // 32 KB, XOR-swizzled
    int rb = blockIdx.x;
    int tid = threadIdx.x, w = tid >> 6, lane = tid & 63;
    int lr = lane & 15, lg = lane >> 4;

#pragma unroll
    for (int i = 0; i < 4; ++i) {
        int g = tid + i * 512;
        int r = g >> 5, c = g & 31;
        int off = (r * 512 + c * 16) ^ ((r & 7) << 4);
        *reinterpret_cast<short8*>(reinterpret_cast<char*>(sX) + off) =
            cvt8(x + (size_t)(rb * 64 + r) * 256 + c * 8);
    }
    __syncthreads();

    f32x4 acc[4][6] = {};
#pragma unroll
    for (int ks = 0; ks < 8; ++ks) {
        int coff = (ks * 32 + lg * 8) * 2;
        short8 xf[4];
#pragma unroll
        for (int rf = 0; rf < 4; ++rf) {
            int row = rf * 16 + lr;
            int off = (row * 512 + coff) ^ ((row & 7) << 4);
            xf[rf] = *reinterpret_cast<const short8*>(
                reinterpret_cast<const char*>(sX) + off);
        }
#pragma unroll
        for (int cf = 0; cf < 6; ++cf) {
            int e = w * 96 + cf * 16 + lr;
            short8 bfr = ldg8(Wb + (size_t)e * 256 + ks * 32 + lg * 8);
#pragma unroll
            for (int rf = 0; rf < 4; ++rf)
                acc[rf][cf] = mfma16(xf[rf], bfr, acc[rf][cf]);
        }
    }

#pragma unroll
    for (int rf = 0; rf < 4; ++rf)
#pragma unroll
        for (int cf = 0; cf < 6; ++cf) {
            int e0c = w * 96 + cf * 16;
            int mat = e0c >> 8;               // 0:Q 1:K 2:V
            int ecol = (e0c & 255) + lr;
            int rbase = rb * 64 + rf * 16 + lg * 4;
            if (mat < 2) {
                unsigned short* dst = (mat == 0) ? Qb : Kb;
#pragma unroll
                for (int r = 0; r < 4; ++r)
                    dst[(size_t)(rbase + r) * 256 + ecol] = f2bf(acc[rf][cf][r]);
            } else {
                int bidx = rbase >> 13, nr = rbase & 8191;
                ushort4_t v;
#pragma unroll
                for (int r = 0; r < 4; ++r) v[r] = f2bf(acc[rf][cf][r]);
                *reinterpret_cast<ushort4_t*>(
                    Vt + ((size_t)bidx * 256 + ecol) * 8192 + nr) = v;
            }
        }
}

// ---------------------------------------------------------------------------
// Kernel 2 (k_zv): per (kt,b): Z[k] = sum_q exp(S[q,k]*SCALE), then
// Vt[b][:, kt*64..+64] *= 1/Z in place. (Proven R10, ~55us.)
// ---------------------------------------------------------------------------
__global__ __launch_bounds__(512, 1) void k_zv(
    const unsigned short* __restrict__ Qb, const unsigned short* __restrict__ Kb,
    unsigned short* __restrict__ Vt)
{
    extern __shared__ char smem[];            // Q dbuf: 2 x 65536 B
    __shared__ float zred[8][32];
    __shared__ float zfin[64];
    const int kt = blockIdx.x, b = blockIdx.y;
    const int tid = threadIdx.x, w = tid >> 6, lane = tid & 63;
    const int lr = lane & 15, lg = lane >> 4;
    const int qs = w & 3, kh = w >> 2;

    short8 kfr[2][8];
#pragma unroll
    for (int kn = 0; kn < 2; ++kn)
#pragma unroll
        for (int ks = 0; ks < 8; ++ks) {
            kfr[kn][ks] = ldg8(
                Kb + (size_t)(b * N_ + kt * 64 + kh * 32 + kn * 16 + lr) * 256
                   + ks * 32 + lg * 8);
            PIN8(kfr[kn][ks]);
        }

    int eoff[8], doff[8];
#pragma unroll
    for (int i = 0; i < 8; ++i) {
        int L = i * 512 + w * 64 + lane;
        int r = L >> 5, c = (L & 31) ^ (r & 7);
        eoff[i] = r * 256 + c * 8;
        doff[i] = L * 16;
    }
    const unsigned short* qbase = Qb + (size_t)b * N_ * 256;

#pragma unroll
    for (int i = 0; i < 8; ++i)
        gll16(qbase + eoff[i], smem + doff[i]);

    float zs0 = 0.f, zs1 = 0.f;
    for (int it = 0; it < 64; ++it) {
        const int cur = it & 1;
        const char* sQ = smem + cur * 65536;

        WAIT_VM0();
        BARRIER();
        __builtin_amdgcn_sched_barrier(0);

        if (it + 1 < 64) {
            const unsigned short* qsrc = qbase + (size_t)(it + 1) * 128 * 256;
            char* nQ = smem + (cur ^ 1) * 65536;
#pragma unroll
            for (int i = 0; i < 8; ++i)
                gll16(qsrc + eoff[i], nQ + doff[i]);
        }

        f32x4 acc[2][2] = {};
        __builtin_amdgcn_s_setprio(1);
#pragma unroll
        for (int ks = 0; ks < 8; ++ks) {
            int coff = (ks * 32 + lg * 8) * 2;
#pragma unroll
            for (int qf = 0; qf < 2; ++qf) {
                int row = qs * 32 + qf * 16 + lr;
                int off = (row * 512 + coff) ^ ((row & 7) << 4);
                short8 qa = *reinterpret_cast<const short8*>(sQ + off);
                acc[qf][0] = mfma16(qa, kfr[0][ks], acc[qf][0]);
                acc[qf][1] = mfma16(qa, kfr[1][ks], acc[qf][1]);
            }
        }
        __builtin_amdgcn_s_setprio(0);

#pragma unroll
        for (int qf = 0; qf < 2; ++qf)
#pragma unroll
            for (int r = 0; r < 4; ++r) {
                zs0 += __expf(acc[qf][0][r] * SCALE);
                zs1 += __expf(acc[qf][1][r] * SCALE);
            }
    }

    zs0 += __shfl_xor(zs0, 16); zs0 += __shfl_xor(zs0, 32);
    zs1 += __shfl_xor(zs1, 16); zs1 += __shfl_xor(zs1, 32);
    if (lg == 0) {
        zred[w][lr]      = zs0;
        zred[w][16 + lr] = zs1;
    }
    __syncthreads();
    if (tid < 64) {
        int kh2 = tid >> 5, kc = tid & 31;
        float z = zred[kh2 * 4 + 0][kc] + zred[kh2 * 4 + 1][kc] +
                  zred[kh2 * 4 + 2][kc] + zred[kh2 * 4 + 3][kc];
        zfin[tid] = 1.0f / z;
    }
    __syncthreads();

#pragma unroll
    for (int i = 0; i < 4; ++i) {
        int G = i * 512 + tid;
        int d = G >> 3, c = G & 7;
        unsigned short* p =
            Vt + ((size_t)b * 256 + d) * 8192 + kt * 64 + c * 8;
        short8 v = *reinterpret_cast<short8*>(p);
        short8 o;
#pragma unroll
        for (int j = 0; j < 8; ++j)
            o[j] = (short)f2bf(bf2f((unsigned short)v[j]) * zfin[c * 8 + j]);
        *reinterpret_cast<short8*>(p) = o;
    }
}

// ---------------------------------------------------------------------------
// Kernel 3 (v11): out[q,d] = sum_k exp(S[q,k]*SCALE) * V'[k,d].
// Grid (128 qt, 2 b), 512 thr (8 waves), qtile 64, BK 64.
// ONE barrier per kt: K dbuf (global_load_lds), P dbuf in LDS, V' read
// straight from global (one 128B line per d-row per kt -> L1-served).
// Per iteration: bar{vm0,lgkm0} -> stage K(kt+1) -> load V(kt-1) -> S(kt)
// MFMAs + PV(kt-1) MFMAs (one region, interleaved) -> exp -> P(kt) write.
// LDS: K 2x32K @0, P 2x8K @65536 = 80 KB.
// ---------------------------------------------------------------------------
__global__ __launch_bounds__(512, 1) void k_attn(
    const unsigned short* __restrict__ Qb, const unsigned short* __restrict__ Kb,
    const unsigned short* __restrict__ Vt, float* __restrict__ out)
{
    extern __shared__ char smem[];
    const int qt = blockIdx.x, b = blockIdx.y;
    const int tid = threadIdx.x, w = tid >> 6, lane = tid & 63;
    const int lr = lane & 15, lg = lane >> 4;
    const int qbase = qt * 64;
    const int wqs = w >> 2;          // q strip (32 q)
    const int wks = w & 3;           // S k-quarter (16 k)
    const int wds = w & 3;           // PV d-quarter (64 d)
    const int q0 = wqs * 32;

    // K staging sources, pre-swizzled
    const unsigned short* srcK[4];
#pragma unroll
    for (int i = 0; i < 4; ++i) {
        int L = w * 256 + i * 64 + lane;
        int r = L >> 5, c = (L & 31) ^ (r & 7);
        srcK[i] = Kb + (size_t)(b * N_ + r) * 256 + c * 8;
    }
    // prologue: stage K(0) -> buffer 0
#pragma unroll
    for (int i = 0; i < 4; ++i) {
        gll16(srcK[i], smem + (size_t)(w * 256 + i * 64) * 16);
        srcK[i] += 64 * 256;
    }

    // V' row pointers for this wave's d-quarter (k advances via offset)
    const unsigned short* vrow[4];
#pragma unroll
    for (int df = 0; df < 4; ++df)
        vrow[df] = Vt + ((size_t)(b * 256 + wds * 64 + df * 16 + lr)) * 8192
                      + lg * 8;

    // hoist Q fragments (32 q x 256 d), pinned
    short8 qfr[2][8];
#pragma unroll
    for (int qf = 0; qf < 2; ++qf) {
        const unsigned short* qrow =
            Qb + (size_t)(b * N_ + qbase + q0 + qf * 16 + lr) * 256;
#pragma unroll
        for (int ks = 0; ks < 8; ++ks) {
            qfr[qf][ks] = ldg8(qrow + ks * 32 + lg * 8);
            PIN8(qfr[qf][ks]);
        }
    }

    f32x4 acco[2][4] = {};

    for (int kt = 0; kt < 128; ++kt) {
        const int cur = kt & 1;
        char* sK  = smem + cur * 32768;
        char* sPw = smem + 65536 + cur * 8192;          // P(kt) write
        const char* sPr = smem + 65536 + (cur ^ 1) * 8192;  // P(kt-1) read

        WAIT_VM0();                  // K(kt) staged (own slices)
        WAIT_LGKM0();                // P(kt-1) writes drained (own)
        BARRIER();                   // chip-wide: staging + P(kt-1) visible
        __builtin_amdgcn_sched_barrier(0);

        // stage K(kt+1) into the other buffer (flies over this iteration)
        if (kt + 1 < 128) {
            char* nK = smem + (cur ^ 1) * 32768;
#pragma unroll
            for (int i = 0; i < 4; ++i) {
                gll16(srcK[i], nK + (size_t)(w * 256 + i * 64) * 16);
                srcK[i] += 64 * 256;
            }
        }

        // V' loads for tile kt-1 (L1/L2-resident; latency hidden by S)
        short8 vfr[8];
        if (kt > 0) {
            int kg = (kt - 1) * 64;
#pragma unroll
            for (int df = 0; df < 4; ++df) {
                vfr[df * 2 + 0] = ldg8(vrow[df] + kg);
                vfr[df * 2 + 1] = ldg8(vrow[df] + kg + 32);
            }
        }

        // ---- one region: S(kt) 16 MFMA + PV(kt-1) 16 MFMA, interleaved ----
        f32x4 sacc[2] = {};
        __builtin_amdgcn_s_setprio(1);
#pragma unroll
        for (int ks = 0; ks < 8; ++ks) {
            int krow = wks * 16 + lr;
            int coff = (ks * 32 + lg * 8) * 2;
            int off = (krow * 512 + coff) ^ ((krow & 7) << 4);
            short8 kb = *reinterpret_cast<const short8*>(sK + off);
            sacc[0] = mfma16(qfr[0][ks], kb, sacc[0]);
            sacc[1] = mfma16(qfr[1][ks], kb, sacc[1]);
        }
        if (kt > 0) {
#pragma unroll
            for (int kk = 0; kk < 2; ++kk) {
                int coff = (kk * 32 + lg * 8) * 2;
                short8 pa[2];
#pragma unroll
                for (int qf = 0; qf < 2; ++qf) {
                    int qq = q0 + qf * 16 + lr;
                    int offa = (qq * 128 + coff) ^ ((qq & 7) << 4);
                    pa[qf] = *reinterpret_cast<const short8*>(sPr + offa);
                }
#pragma unroll
                for (int df = 0; df < 4; ++df) {
                    acco[0][df] = mfma16(pa[0], vfr[df * 2 + kk], acco[0][df]);
                    acco[1][df] = mfma16(pa[1], vfr[df * 2 + kk], acco[1][df]);
                }
            }
        }
        __builtin_amdgcn_s_setprio(0);

        // ---- P(kt) = exp(S*SCALE) -> sPw (bf16, swizzled) ----
#pragma unroll
        for (int qf = 0; qf < 2; ++qf)
#pragma unroll
            for (int r = 0; r < 4; ++r) {
                float p = __expf(sacc[qf][r] * SCALE);
                int q = q0 + qf * 16 + lg * 4 + r;
                int kcol = wks * 16 + lr;
                int off = (q * 128 + kcol * 2) ^ ((q & 7) << 4);
                *reinterpret_cast<unsigned short*>(sPw + off) = f2bf(p);
            }
    }

    // ---- epilogue: PV(127) ----
    WAIT_LGKM0();
    BARRIER();
    {
        const char* sPr = smem + 65536 + (127 & 1) * 8192;
        int kg = 127 * 64;
        short8 vfr[8];
#pragma unroll
        for (int df = 0; df < 4; ++df) {
            vfr[df * 2 + 0] = ldg8(vrow[df] + kg);
            vfr[df * 2 + 1] = ldg8(vrow[df] + kg + 32);
        }
#pragma unroll
        for (int kk = 0; kk < 2; ++kk) {
            int coff = (kk * 32 + lg * 8) * 2;
            short8 pa[2];
#pragma unroll
            for (int qf = 0; qf < 2; ++qf) {
                int qq = q0 + qf * 16 + lr;
                int offa = (qq * 128 + coff) ^ ((qq & 7) << 4);
                pa[qf] = *reinterpret_cast<const short8*>(sPr + offa);
            }
#pragma unroll
            for (int df = 0; df < 4; ++df) {
                acco[0][df] = mfma16(pa[0], vfr[df * 2 + kk], acco[0][df]);
                acco[1][df] = mfma16(pa[1], vfr[df * 2 + kk], acco[1][df]);
            }
        }
    }

    // epilogue: f32 store
#pragma unroll
    for (int qf = 0; qf < 2; ++qf)
#pragma unroll
        for (int df = 0; df < 4; ++df) {
            int d = wds * 64 + df * 16 + lr;
            int q0r = qbase + q0 + qf * 16 + lg * 4;
#pragma unroll
            for (int r = 0; r < 4; ++r)
                out[(size_t)(b * N_ + q0r + r) * 256 + d] = acco[qf][df][r];
        }
}

extern "C" void kernel_launch(void* const* d_in, const int* in_sizes, int n_in,
                              void* d_out, int out_size, void* d_ws, size_t ws_size,
                              hipStream_t stream)
{
    const float* x  = (const float*)d_in[0];
    const float* Wq = (const float*)d_in[1];
    const float* Wk = (const float*)d_in[2];
    const float* Wv = (const float*)d_in[3];

    char* ws = (char*)d_ws;
    unsigned short* Qb = (unsigned short*)(ws);              //  8 MB
    unsigned short* Kb = (unsigned short*)(ws + 8388608);    //  8 MB
    unsigned short* Vt = (unsigned short*)(ws + 16777216);   //  8 MB
    unsigned short* Wb = (unsigned short*)(ws + 25165824);   // 384 KB
    float* out = (float*)d_out;

    k_cvtw<<<dim3(96), dim3(256), 0, stream>>>(Wq, Wk, Wv, Wb);
    k_proj<<<dim3(256), dim3(512), 0, stream>>>(x, Wb, Qb, Kb, Vt);

    hipFuncSetAttribute((const void*)k_zv,
                        hipFuncAttributeMaxDynamicSharedMemorySize, 131072);
    k_zv<<<dim3(128, 2), dim3(512), 131072, stream>>>(Qb, Kb, Vt);

    hipFuncSetAttribute((const void*)k_attn,
                        hipFuncAttributeMaxDynamicSharedMemorySize, 81920);
    k_attn<<<dim3(128, 2), dim3(512), 81920, stream>>>(Qb, Kb, Vt, out);
}

// Round 12
// 425.329 us; speedup vs baseline: 1.0566x; 1.0566x over previous
//
#include <hip/hip_runtime.h>
#include <hip/hip_bf16.h>

// Attention with softmax over the QUERY axis (axis=1):
//   attn[:,q,k] = exp(S[q,k]) / Z[k],  Z[k] = sum_q exp(S[q,k])
//   out = expS @ (diag(1/Z) V)   -- 1/Z folded into V by k_zv's epilogue.
// B=2, N=8192, D=256. All matmuls via mfma_f32_16x16x32_bf16.
// R12: R11's 1-barrier deferred-PV structure with CORRECT vmcnt pipelining:
// V(t) is prefetched during iteration t into register dbuf (vfA/vfB, static
// names) and consumed in t+1, so the single top-of-iteration vmcnt(0) drains
// exactly {K(t) staging, V(t-1)} and nothing stalls mid-iteration. (R11 bug:
// V issued after K staging and consumed same-iteration -> the implicit wait
// drained the K prefetch every tile.)

#define N_ 8192
#define SCALE 0.0625f

typedef __attribute__((ext_vector_type(8))) short short8;
typedef __attribute__((ext_vector_type(4))) float f32x4;
typedef __attribute__((ext_vector_type(4))) unsigned short ushort4_t;

__device__ inline unsigned short f2bf(float f) {
    unsigned int x = __float_as_uint(f);
    unsigned int r = (x + 0x7fffu + ((x >> 16) & 1u)) >> 16;  // RNE
    return (unsigned short)r;
}

__device__ inline short8 ldg8(const unsigned short* p) {
    return *reinterpret_cast<const short8*>(p);
}

__device__ inline short8 cvt8(const float* p) {
    float4 a = *(const float4*)p;
    float4 b = *(const float4*)(p + 4);
    short8 r;
    r[0] = (short)f2bf(a.x); r[1] = (short)f2bf(a.y);
    r[2] = (short)f2bf(a.z); r[3] = (short)f2bf(a.w);
    r[4] = (short)f2bf(b.x); r[5] = (short)f2bf(b.y);
    r[6] = (short)f2bf(b.z); r[7] = (short)f2bf(b.w);
    return r;
}

__device__ inline f32x4 mfma16(short8 a, short8 b, f32x4 c) {
    return __builtin_amdgcn_mfma_f32_16x16x32_bf16(a, b, c, 0, 0, 0);
}

__device__ inline float bf2f(unsigned short u) {
    return __uint_as_float(((unsigned)u) << 16);
}

#define PIN8(v) asm volatile("" : "+v"(v))

typedef __attribute__((address_space(3))) unsigned int lds_u32;
typedef __attribute__((address_space(1))) const unsigned int glb_u32;
__device__ __forceinline__ void gll16(const void* g, void* l) {
    __builtin_amdgcn_global_load_lds((glb_u32*)g, (lds_u32*)l, 16, 0, 0);
}
#define WAIT_VM0()   asm volatile("s_waitcnt vmcnt(0)" ::: "memory")
#define WAIT_LGKM0() asm volatile("s_waitcnt lgkmcnt(0)" ::: "memory")
#define BARRIER()    __builtin_amdgcn_s_barrier()

// ---------------------------------------------------------------------------
// Kernel 0: W (3 x 256x256 f32) -> Wb (768x256 bf16), concatenated Q|K|V.
// ---------------------------------------------------------------------------
__global__ __launch_bounds__(256) void k_cvtw(
    const float* __restrict__ Wq, const float* __restrict__ Wk,
    const float* __restrict__ Wv, unsigned short* __restrict__ Wb)
{
    int t = blockIdx.x * 256 + threadIdx.x;
    int e8 = t * 8;
    const float* src = (e8 < 65536) ? Wq + e8
                     : (e8 < 131072) ? Wk + (e8 - 65536)
                                     : Wv + (e8 - 131072);
    *reinterpret_cast<short8*>(Wb + e8) = cvt8(src);
}

// ---------------------------------------------------------------------------
// Kernel 1: QKV projection, x read ONCE (proven R5).
// ---------------------------------------------------------------------------
__global__ __launch_bounds__(512) void k_proj(
    const float* __restrict__ x, const unsigned short* __restrict__ Wb,
    unsigned short* __restrict__ Qb, unsigned short* __restrict__ Kb,
    unsigned short* __restrict__ Vt)
{
    __shared__ unsigned short sX[64 * 256];   // 32 KB, XOR-swizzled
    int rb = blockIdx.x;
    int tid = threadIdx.x, w = tid >> 6, lane = tid & 63;
    int lr = lane & 15, lg = lane >> 4;

#pragma unroll
    for (int i = 0; i < 4; ++i) {
        int g = tid + i * 512;
        int r = g >> 5, c = g & 31;
        int off = (r * 512 + c * 16) ^ ((r & 7) << 4);
        *reinterpret_cast<short8*>(reinterpret_cast<char*>(sX) + off) =
            cvt8(x + (size_t)(rb * 64 + r) * 256 + c * 8);
    }
    __syncthreads();

    f32x4 acc[4][6] = {};
#pragma unroll
    for (int ks = 0; ks < 8; ++ks) {
        int coff = (ks * 32 + lg * 8) * 2;
        short8 xf[4];
#pragma unroll
        for (int rf = 0; rf < 4; ++rf) {
            int row = rf * 16 + lr;
            int off = (row * 512 + coff) ^ ((row & 7) << 4);
            xf[rf] = *reinterpret_cast<const short8*>(
                reinterpret_cast<const char*>(sX) + off);
        }
#pragma unroll
        for (int cf = 0; cf < 6; ++cf) {
            int e = w * 96 + cf * 16 + lr;
            short8 bfr = ldg8(Wb + (size_t)e * 256 + ks * 32 + lg * 8);
#pragma unroll
            for (int rf = 0; rf < 4; ++rf)
                acc[rf][cf] = mfma16(xf[rf], bfr, acc[rf][cf]);
        }
    }

#pragma unroll
    for (int rf = 0; rf < 4; ++rf)
#pragma unroll
        for (int cf = 0; cf < 6; ++cf) {
            int e0c = w * 96 + cf * 16;
            int mat = e0c >> 8;               // 0:Q 1:K 2:V
            int ecol = (e0c & 255) + lr;
            int rbase = rb * 64 + rf * 16 + lg * 4;
            if (mat < 2) {
                unsigned short* dst = (mat == 0) ? Qb : Kb;
#pragma unroll
                for (int r = 0; r < 4; ++r)
                    dst[(size_t)(rbase + r) * 256 + ecol] = f2bf(acc[rf][cf][r]);
            } else {
                int bidx = rbase >> 13, nr = rbase & 8191;
                ushort4_t v;
#pragma unroll
                for (int r = 0; r < 4; ++r) v[r] = f2bf(acc[rf][cf][r]);
                *reinterpret_cast<ushort4_t*>(
                    Vt + ((size_t)bidx * 256 + ecol) * 8192 + nr) = v;
            }
        }
}

// ---------------------------------------------------------------------------
// Kernel 2 (k_zv): per (kt,b): Z[k] = sum_q exp(S[q,k]*SCALE), then
// Vt[b][:, kt*64..+64] *= 1/Z in place. (Proven R10, ~55us.)
// ---------------------------------------------------------------------------
__global__ __launch_bounds__(512, 1) void k_zv(
    const unsigned short* __restrict__ Qb, const unsigned short* __restrict__ Kb,
    unsigned short* __restrict__ Vt)
{
    extern __shared__ char smem[];            // Q dbuf: 2 x 65536 B
    __shared__ float zred[8][32];
    __shared__ float zfin[64];
    const int kt = blockIdx.x, b = blockIdx.y;
    const int tid = threadIdx.x, w = tid >> 6, lane = tid & 63;
    const int lr = lane & 15, lg = lane >> 4;
    const int qs = w & 3, kh = w >> 2;

    short8 kfr[2][8];
#pragma unroll
    for (int kn = 0; kn < 2; ++kn)
#pragma unroll
        for (int ks = 0; ks < 8; ++ks) {
            kfr[kn][ks] = ldg8(
                Kb + (size_t)(b * N_ + kt * 64 + kh * 32 + kn * 16 + lr) * 256
                   + ks * 32 + lg * 8);
            PIN8(kfr[kn][ks]);
        }

    int eoff[8], doff[8];
#pragma unroll
    for (int i = 0; i < 8; ++i) {
        int L = i * 512 + w * 64 + lane;
        int r = L >> 5, c = (L & 31) ^ (r & 7);
        eoff[i] = r * 256 + c * 8;
        doff[i] = L * 16;
    }
    const unsigned short* qbase = Qb + (size_t)b * N_ * 256;

#pragma unroll
    for (int i = 0; i < 8; ++i)
        gll16(qbase + eoff[i], smem + doff[i]);

    float zs0 = 0.f, zs1 = 0.f;
    for (int it = 0; it < 64; ++it) {
        const int cur = it & 1;
        const char* sQ = smem + cur * 65536;

        WAIT_VM0();
        BARRIER();
        __builtin_amdgcn_sched_barrier(0);

        if (it + 1 < 64) {
            const unsigned short* qsrc = qbase + (size_t)(it + 1) * 128 * 256;
            char* nQ = smem + (cur ^ 1) * 65536;
#pragma unroll
            for (int i = 0; i < 8; ++i)
                gll16(qsrc + eoff[i], nQ + doff[i]);
        }

        f32x4 acc[2][2] = {};
        __builtin_amdgcn_s_setprio(1);
#pragma unroll
        for (int ks = 0; ks < 8; ++ks) {
            int coff = (ks * 32 + lg * 8) * 2;
#pragma unroll
            for (int qf = 0; qf < 2; ++qf) {
                int row = qs * 32 + qf * 16 + lr;
                int off = (row * 512 + coff) ^ ((row & 7) << 4);
                short8 qa = *reinterpret_cast<const short8*>(sQ + off);
                acc[qf][0] = mfma16(qa, kfr[0][ks], acc[qf][0]);
                acc[qf][1] = mfma16(qa, kfr[1][ks], acc[qf][1]);
            }
        }
        __builtin_amdgcn_s_setprio(0);

#pragma unroll
        for (int qf = 0; qf < 2; ++qf)
#pragma unroll
            for (int r = 0; r < 4; ++r) {
                zs0 += __expf(acc[qf][0][r] * SCALE);
                zs1 += __expf(acc[qf][1][r] * SCALE);
            }
    }

    zs0 += __shfl_xor(zs0, 16); zs0 += __shfl_xor(zs0, 32);
    zs1 += __shfl_xor(zs1, 16); zs1 += __shfl_xor(zs1, 32);
    if (lg == 0) {
        zred[w][lr]      = zs0;
        zred[w][16 + lr] = zs1;
    }
    __syncthreads();
    if (tid < 64) {
        int kh2 = tid >> 5, kc = tid & 31;
        float z = zred[kh2 * 4 + 0][kc] + zred[kh2 * 4 + 1][kc] +
                  zred[kh2 * 4 + 2][kc] + zred[kh2 * 4 + 3][kc];
        zfin[tid] = 1.0f / z;
    }
    __syncthreads();

#pragma unroll
    for (int i = 0; i < 4; ++i) {
        int G = i * 512 + tid;
        int d = G >> 3, c = G & 7;
        unsigned short* p =
            Vt + ((size_t)b * 256 + d) * 8192 + kt * 64 + c * 8;
        short8 v = *reinterpret_cast<short8*>(p);
        short8 o;
#pragma unroll
        for (int j = 0; j < 8; ++j)
            o[j] = (short)f2bf(bf2f((unsigned short)v[j]) * zfin[c * 8 + j]);
        *reinterpret_cast<short8*>(p) = o;
    }
}

// ---------------------------------------------------------------------------
// Kernel 3 (v12): out[q,d] = sum_k exp(S[q,k]*SCALE) * V'[k,d].
// Grid (128 qt, 2 b), 512 thr (8 waves), qtile 64, BK 64.
// One barrier/kt. Pipeline (iteration t):
//   vmcnt(0)+lgkmcnt(0)+barrier  -> {K(t) staged, V(t-1) in regs, P(t-1) vis}
//   issue K(t+1) staging; issue V(t) loads into reg dbuf (vfA/vfB);
//   S(t) MFMAs + PV(t-1) MFMAs in one region; exp -> P(t) into P-dbuf.
// LDS: K 2x32K @0, P 2x8K @65536 = 80 KB.
// ---------------------------------------------------------------------------
__global__ __launch_bounds__(512, 1) void k_attn(
    const unsigned short* __restrict__ Qb, const unsigned short* __restrict__ Kb,
    const unsigned short* __restrict__ Vt, float* __restrict__ out)
{
    extern __shared__ char smem[];
    const int qt = blockIdx.x, b = blockIdx.y;
    const int tid = threadIdx.x, w = tid >> 6, lane = tid & 63;
    const int lr = lane & 15, lg = lane >> 4;
    const int qbase = qt * 64;
    const int wqs = w >> 2;          // q strip (32 q)
    const int wks = w & 3;           // S k-quarter (16 k)
    const int wds = w & 3;           // PV d-quarter (64 d)
    const int q0 = wqs * 32;

    // K staging sources, pre-swizzled
    const unsigned short* srcK[4];
#pragma unroll
    for (int i = 0; i < 4; ++i) {
        int L = w * 256 + i * 64 + lane;
        int r = L >> 5, c = (L & 31) ^ (r & 7);
        srcK[i] = Kb + (size_t)(b * N_ + r) * 256 + c * 8;
    }
    // prologue: stage K(0) -> buffer 0
#pragma unroll
    for (int i = 0; i < 4; ++i) {
        gll16(srcK[i], smem + (size_t)(w * 256 + i * 64) * 16);
        srcK[i] += 64 * 256;
    }

    // V' row pointers for this wave's d-quarter
    const unsigned short* vrow[4];
#pragma unroll
    for (int df = 0; df < 4; ++df)
        vrow[df] = Vt + ((size_t)(b * 256 + wds * 64 + df * 16 + lr)) * 8192
                      + lg * 8;

    // hoist Q fragments (32 q x 256 d), pinned
    short8 qfr[2][8];
#pragma unroll
    for (int qf = 0; qf < 2; ++qf) {
        const unsigned short* qrow =
            Qb + (size_t)(b * N_ + qbase + q0 + qf * 16 + lr) * 256;
#pragma unroll
        for (int ks = 0; ks < 8; ++ks) {
            qfr[qf][ks] = ldg8(qrow + ks * 32 + lg * 8);
            PIN8(qfr[qf][ks]);
        }
    }

    f32x4 acco[2][4] = {};
    short8 vfA[8], vfB[8];
    int kg = 0;

    // CUR: LDS buffer parity of tile t. VLOAD: reg buffer receiving V(t).
    // VCONS: reg buffer holding V(t-1). DO_STAGE: stage K(t+1). DO_PV: t>0.
#define AITER(CUR, VLOAD, VCONS, DO_STAGE, DO_PV)                             \
    do {                                                                      \
        WAIT_VM0();                                                           \
        WAIT_LGKM0();                                                         \
        BARRIER();                                                            \
        __builtin_amdgcn_sched_barrier(0);                                    \
        char* sK  = smem + (CUR) * 32768;                                     \
        char* sPw = smem + 65536 + (CUR) * 8192;                              \
        const char* sPr = smem + 65536 + ((CUR) ^ 1) * 8192;                  \
        if (DO_STAGE) {                                                       \
            char* nK = smem + ((CUR) ^ 1) * 32768;                            \
            _Pragma("unroll") for (int i = 0; i < 4; ++i) {                   \
                gll16(srcK[i], nK + (size_t)(w * 256 + i * 64) * 16);         \
                srcK[i] += 64 * 256;                                          \
            }                                                                 \
        }                                                                     \
        _Pragma("unroll") for (int df = 0; df < 4; ++df) {                    \
            VLOAD[df * 2 + 0] = ldg8(vrow[df] + kg);                          \
            VLOAD[df * 2 + 1] = ldg8(vrow[df] + kg + 32);                     \
        }                                                                     \
        kg += 64;                                                             \
        f32x4 sacc[2] = {};                                                   \
        __builtin_amdgcn_s_setprio(1);                                        \
        _Pragma("unroll") for (int ks = 0; ks < 8; ++ks) {                    \
            int krow = wks * 16 + lr;                                         \
            int coff = (ks * 32 + lg * 8) * 2;                                \
            int off = (krow * 512 + coff) ^ ((krow & 7) << 4);                \
            short8 kb = *reinterpret_cast<const short8*>(sK + off);           \
            sacc[0] = mfma16(qfr[0][ks], kb, sacc[0]);                        \
            sacc[1] = mfma16(qfr[1][ks], kb, sacc[1]);                        \
        }                                                                     \
        if (DO_PV) {                                                          \
            _Pragma("unroll") for (int kk = 0; kk < 2; ++kk) {                \
                int coff = (kk * 32 + lg * 8) * 2;                            \
                short8 pa0, pa1;                                              \
                {                                                             \
                    int qq = q0 + lr;                                         \
                    int offa = (qq * 128 + coff) ^ ((qq & 7) << 4);           \
                    pa0 = *reinterpret_cast<const short8*>(sPr + offa);       \
                }                                                             \
                {                                                             \
                    int qq = q0 + 16 + lr;                                    \
                    int offa = (qq * 128 + coff) ^ ((qq & 7) << 4);           \
                    pa1 = *reinterpret_cast<const short8*>(sPr + offa);       \
                }                                                             \
                _Pragma("unroll") for (int df = 0; df < 4; ++df) {            \
                    acco[0][df] = mfma16(pa0, VCONS[df * 2 + kk], acco[0][df]); \
                    acco[1][df] = mfma16(pa1, VCONS[df * 2 + kk], acco[1][df]); \
                }                                                             \
            }                                                                 \
        }                                                                     \
        __builtin_amdgcn_s_setprio(0);                                        \
        _Pragma("unroll") for (int qf = 0; qf < 2; ++qf)                      \
            _Pragma("unroll") for (int r = 0; r < 4; ++r) {                   \
                float p = __expf(sacc[qf][r] * SCALE);                        \
                int q = q0 + qf * 16 + lg * 4 + r;                            \
                int kcol = wks * 16 + lr;                                     \
                int off = (q * 128 + kcol * 2) ^ ((q & 7) << 4);              \
                *reinterpret_cast<unsigned short*>(sPw + off) = f2bf(p);      \
            }                                                                 \
    } while (0)

    // t = 0: stage K(1), load V(0)->vfA, no PV
    AITER(0, vfA, vfB, true, false);
    // t = 1..126: 63 pairs (odd t loads vfB consumes vfA; even t vice versa)
#pragma unroll 1
    for (int t2 = 0; t2 < 63; ++t2) {
        AITER(1, vfB, vfA, true, true);
        AITER(0, vfA, vfB, true, true);
    }
    // t = 127: no staging, load V(127)->vfB, PV(126) from vfA
    AITER(1, vfB, vfA, false, true);
#undef AITER

    // final PV(127): P in sP[1], V in vfB
    WAIT_VM0();
    WAIT_LGKM0();
    BARRIER();
    {
        const char* sPr = smem + 65536 + 1 * 8192;
#pragma unroll
        for (int kk = 0; kk < 2; ++kk) {
            int coff = (kk * 32 + lg * 8) * 2;
            short8 pa0, pa1;
            {
                int qq = q0 + lr;
                int offa = (qq * 128 + coff) ^ ((qq & 7) << 4);
                pa0 = *reinterpret_cast<const short8*>(sPr + offa);
            }
            {
                int qq = q0 + 16 + lr;
                int offa = (qq * 128 + coff) ^ ((qq & 7) << 4);
                pa1 = *reinterpret_cast<const short8*>(sPr + offa);
            }
#pragma unroll
            for (int df = 0; df < 4; ++df) {
                acco[0][df] = mfma16(pa0, vfB[df * 2 + kk], acco[0][df]);
                acco[1][df] = mfma16(pa1, vfB[df * 2 + kk], acco[1][df]);
            }
        }
    }

    // epilogue: f32 store
#pragma unroll
    for (int qf = 0; qf < 2; ++qf)
#pragma unroll
        for (int df = 0; df < 4; ++df) {
            int d = wds * 64 + df * 16 + lr;
            int q0r = qbase + q0 + qf * 16 + lg * 4;
#pragma unroll
            for (int r = 0; r < 4; ++r)
                out[(size_t)(b * N_ + q0r + r) * 256 + d] = acco[qf][df][r];
        }
}

extern "C" void kernel_launch(void* const* d_in, const int* in_sizes, int n_in,
                              void* d_out, int out_size, void* d_ws, size_t ws_size,
                              hipStream_t stream)
{
    const float* x  = (const float*)d_in[0];
    const float* Wq = (const float*)d_in[1];
    const float* Wk = (const float*)d_in[2];
    const float* Wv = (const float*)d_in[3];

    char* ws = (char*)d_ws;
    unsigned short* Qb = (unsigned short*)(ws);              //  8 MB
    unsigned short* Kb = (unsigned short*)(ws + 8388608);    //  8 MB
    unsigned short* Vt = (unsigned short*)(ws + 16777216);   //  8 MB
    unsigned short* Wb = (unsigned short*)(ws + 25165824);   // 384 KB
    float* out = (float*)d_out;

    k_cvtw<<<dim3(96), dim3(256), 0, stream>>>(Wq, Wk, Wv, Wb);
    k_proj<<<dim3(256), dim3(512), 0, stream>>>(x, Wb, Qb, Kb, Vt);

    hipFuncSetAttribute((const void*)k_zv,
                        hipFuncAttributeMaxDynamicSharedMemorySize, 131072);
    k_zv<<<dim3(128, 2), dim3(512), 131072, stream>>>(Qb, Kb, Vt);

    hipFuncSetAttribute((const void*)k_attn,
                        hipFuncAttributeMaxDynamicSharedMemorySize, 81920);
    k_attn<<<dim3(128, 2), dim3(512), 81920, stream>>>(Qb, Kb, Vt, out);
}

// Round 13
// 412.145 us; speedup vs baseline: 1.0904x; 1.0320x over previous
//
#include <hip/hip_runtime.h>
#include <hip/hip_bf16.h>

// Attention with softmax over the QUERY axis (axis=1):
//   attn[:,q,k] = exp(S[q,k]) / Z[k],  Z[k] = sum_q exp(S[q,k])
//   out = expS @ (diag(1/Z) V)   -- 1/Z folded into V by k_zv's epilogue.
// B=2, N=8192, D=256. All matmuls via mfma_f32_16x16x32_bf16.
// R13: proven R9 2-barrier k_attn, with V moved LDS->registers. V(t) loads
// are issued BEFORE K(t+1) staging (vmcnt is a FIFO: compiler's auto-wait
// before PV becomes a counted vmcnt(4), keeping the K prefetch in flight --
// R11 had the order reversed, which drained the prefetch every tile).
// LDS port load drops ~3170 -> ~2150 cy/kt (V: 32KB DMA + 64 b128 reads gone).

#define N_ 8192
#define SCALE 0.0625f

typedef __attribute__((ext_vector_type(8))) short short8;
typedef __attribute__((ext_vector_type(4))) float f32x4;
typedef __attribute__((ext_vector_type(4))) unsigned short ushort4_t;

__device__ inline unsigned short f2bf(float f) {
    unsigned int x = __float_as_uint(f);
    unsigned int r = (x + 0x7fffu + ((x >> 16) & 1u)) >> 16;  // RNE
    return (unsigned short)r;
}

__device__ inline short8 ldg8(const unsigned short* p) {
    return *reinterpret_cast<const short8*>(p);
}

__device__ inline short8 cvt8(const float* p) {
    float4 a = *(const float4*)p;
    float4 b = *(const float4*)(p + 4);
    short8 r;
    r[0] = (short)f2bf(a.x); r[1] = (short)f2bf(a.y);
    r[2] = (short)f2bf(a.z); r[3] = (short)f2bf(a.w);
    r[4] = (short)f2bf(b.x); r[5] = (short)f2bf(b.y);
    r[6] = (short)f2bf(b.z); r[7] = (short)f2bf(b.w);
    return r;
}

__device__ inline f32x4 mfma16(short8 a, short8 b, f32x4 c) {
    return __builtin_amdgcn_mfma_f32_16x16x32_bf16(a, b, c, 0, 0, 0);
}

__device__ inline float bf2f(unsigned short u) {
    return __uint_as_float(((unsigned)u) << 16);
}

#define PIN8(v) asm volatile("" : "+v"(v))

typedef __attribute__((address_space(3))) unsigned int lds_u32;
typedef __attribute__((address_space(1))) const unsigned int glb_u32;
__device__ __forceinline__ void gll16(const void* g, void* l) {
    __builtin_amdgcn_global_load_lds((glb_u32*)g, (lds_u32*)l, 16, 0, 0);
}
#define WAIT_VM0()   asm volatile("s_waitcnt vmcnt(0)" ::: "memory")
#define WAIT_LGKM0() asm volatile("s_waitcnt lgkmcnt(0)" ::: "memory")
#define BARRIER()    __builtin_amdgcn_s_barrier()

// ---------------------------------------------------------------------------
// Kernel 0: W (3 x 256x256 f32) -> Wb (768x256 bf16), concatenated Q|K|V.
// ---------------------------------------------------------------------------
__global__ __launch_bounds__(256) void k_cvtw(
    const float* __restrict__ Wq, const float* __restrict__ Wk,
    const float* __restrict__ Wv, unsigned short* __restrict__ Wb)
{
    int t = blockIdx.x * 256 + threadIdx.x;
    int e8 = t * 8;
    const float* src = (e8 < 65536) ? Wq + e8
                     : (e8 < 131072) ? Wk + (e8 - 65536)
                                     : Wv + (e8 - 131072);
    *reinterpret_cast<short8*>(Wb + e8) = cvt8(src);
}

// ---------------------------------------------------------------------------
// Kernel 1: QKV projection, x read ONCE (proven R5).
// ---------------------------------------------------------------------------
__global__ __launch_bounds__(512) void k_proj(
    const float* __restrict__ x, const unsigned short* __restrict__ Wb,
    unsigned short* __restrict__ Qb, unsigned short* __restrict__ Kb,
    unsigned short* __restrict__ Vt)
{
    __shared__ unsigned short sX[64 * 256];   // 32 KB, XOR-swizzled
    int rb = blockIdx.x;
    int tid = threadIdx.x, w = tid >> 6, lane = tid & 63;
    int lr = lane & 15, lg = lane >> 4;

#pragma unroll
    for (int i = 0; i < 4; ++i) {
        int g = tid + i * 512;
        int r = g >> 5, c = g & 31;
        int off = (r * 512 + c * 16) ^ ((r & 7) << 4);
        *reinterpret_cast<short8*>(reinterpret_cast<char*>(sX) + off) =
            cvt8(x + (size_t)(rb * 64 + r) * 256 + c * 8);
    }
    __syncthreads();

    f32x4 acc[4][6] = {};
#pragma unroll
    for (int ks = 0; ks < 8; ++ks) {
        int coff = (ks * 32 + lg * 8) * 2;
        short8 xf[4];
#pragma unroll
        for (int rf = 0; rf < 4; ++rf) {
            int row = rf * 16 + lr;
            int off = (row * 512 + coff) ^ ((row & 7) << 4);
            xf[rf] = *reinterpret_cast<const short8*>(
                reinterpret_cast<const char*>(sX) + off);
        }
#pragma unroll
        for (int cf = 0; cf < 6; ++cf) {
            int e = w * 96 + cf * 16 + lr;
            short8 bfr = ldg8(Wb + (size_t)e * 256 + ks * 32 + lg * 8);
#pragma unroll
            for (int rf = 0; rf < 4; ++rf)
                acc[rf][cf] = mfma16(xf[rf], bfr, acc[rf][cf]);
        }
    }

#pragma unroll
    for (int rf = 0; rf < 4; ++rf)
#pragma unroll
        for (int cf = 0; cf < 6; ++cf) {
            int e0c = w * 96 + cf * 16;
            int mat = e0c >> 8;               // 0:Q 1:K 2:V
            int ecol = (e0c & 255) + lr;
            int rbase = rb * 64 + rf * 16 + lg * 4;
            if (mat < 2) {
                unsigned short* dst = (mat == 0) ? Qb : Kb;
#pragma unroll
                for (int r = 0; r < 4; ++r)
                    dst[(size_t)(rbase + r) * 256 + ecol] = f2bf(acc[rf][cf][r]);
            } else {
                int bidx = rbase >> 13, nr = rbase & 8191;
                ushort4_t v;
#pragma unroll
                for (int r = 0; r < 4; ++r) v[r] = f2bf(acc[rf][cf][r]);
                *reinterpret_cast<ushort4_t*>(
                    Vt + ((size_t)bidx * 256 + ecol) * 8192 + nr) = v;
            }
        }
}

// ---------------------------------------------------------------------------
// Kernel 2 (k_zv): per (kt,b): Z[k] = sum_q exp(S[q,k]*SCALE), then
// Vt[b][:, kt*64..+64] *= 1/Z in place. (Proven R10, ~55us.)
// ---------------------------------------------------------------------------
__global__ __launch_bounds__(512, 1) void k_zv(
    const unsigned short* __restrict__ Qb, const unsigned short* __restrict__ Kb,
    unsigned short* __restrict__ Vt)
{
    extern __shared__ char smem[];            // Q dbuf: 2 x 65536 B
    __shared__ float zred[8][32];
    __shared__ float zfin[64];
    const int kt = blockIdx.x, b = blockIdx.y;
    const int tid = threadIdx.x, w = tid >> 6, lane = tid & 63;
    const int lr = lane & 15, lg = lane >> 4;
    const int qs = w & 3, kh = w >> 2;

    short8 kfr[2][8];
#pragma unroll
    for (int kn = 0; kn < 2; ++kn)
#pragma unroll
        for (int ks = 0; ks < 8; ++ks) {
            kfr[kn][ks] = ldg8(
                Kb + (size_t)(b * N_ + kt * 64 + kh * 32 + kn * 16 + lr) * 256
                   + ks * 32 + lg * 8);
            PIN8(kfr[kn][ks]);
        }

    int eoff[8], doff[8];
#pragma unroll
    for (int i = 0; i < 8; ++i) {
        int L = i * 512 + w * 64 + lane;
        int r = L >> 5, c = (L & 31) ^ (r & 7);
        eoff[i] = r * 256 + c * 8;
        doff[i] = L * 16;
    }
    const unsigned short* qbase = Qb + (size_t)b * N_ * 256;

#pragma unroll
    for (int i = 0; i < 8; ++i)
        gll16(qbase + eoff[i], smem + doff[i]);

    float zs0 = 0.f, zs1 = 0.f;
    for (int it = 0; it < 64; ++it) {
        const int cur = it & 1;
        const char* sQ = smem + cur * 65536;

        WAIT_VM0();
        BARRIER();
        __builtin_amdgcn_sched_barrier(0);

        if (it + 1 < 64) {
            const unsigned short* qsrc = qbase + (size_t)(it + 1) * 128 * 256;
            char* nQ = smem + (cur ^ 1) * 65536;
#pragma unroll
            for (int i = 0; i < 8; ++i)
                gll16(qsrc + eoff[i], nQ + doff[i]);
        }

        f32x4 acc[2][2] = {};
        __builtin_amdgcn_s_setprio(1);
#pragma unroll
        for (int ks = 0; ks < 8; ++ks) {
            int coff = (ks * 32 + lg * 8) * 2;
#pragma unroll
            for (int qf = 0; qf < 2; ++qf) {
                int row = qs * 32 + qf * 16 + lr;
                int off = (row * 512 + coff) ^ ((row & 7) << 4);
                short8 qa = *reinterpret_cast<const short8*>(sQ + off);
                acc[qf][0] = mfma16(qa, kfr[0][ks], acc[qf][0]);
                acc[qf][1] = mfma16(qa, kfr[1][ks], acc[qf][1]);
            }
        }
        __builtin_amdgcn_s_setprio(0);

#pragma unroll
        for (int qf = 0; qf < 2; ++qf)
#pragma unroll
            for (int r = 0; r < 4; ++r) {
                zs0 += __expf(acc[qf][0][r] * SCALE);
                zs1 += __expf(acc[qf][1][r] * SCALE);
            }
    }

    zs0 += __shfl_xor(zs0, 16); zs0 += __shfl_xor(zs0, 32);
    zs1 += __shfl_xor(zs1, 16); zs1 += __shfl_xor(zs1, 32);
    if (lg == 0) {
        zred[w][lr]      = zs0;
        zred[w][16 + lr] = zs1;
    }
    __syncthreads();
    if (tid < 64) {
        int kh2 = tid >> 5, kc = tid & 31;
        float z = zred[kh2 * 4 + 0][kc] + zred[kh2 * 4 + 1][kc] +
                  zred[kh2 * 4 + 2][kc] + zred[kh2 * 4 + 3][kc];
        zfin[tid] = 1.0f / z;
    }
    __syncthreads();

#pragma unroll
    for (int i = 0; i < 4; ++i) {
        int G = i * 512 + tid;
        int d = G >> 3, c = G & 7;
        unsigned short* p =
            Vt + ((size_t)b * 256 + d) * 8192 + kt * 64 + c * 8;
        short8 v = *reinterpret_cast<short8*>(p);
        short8 o;
#pragma unroll
        for (int j = 0; j < 8; ++j)
            o[j] = (short)f2bf(bf2f((unsigned short)v[j]) * zfin[c * 8 + j]);
        *reinterpret_cast<short8*>(p) = o;
    }
}

// ---------------------------------------------------------------------------
// Kernel 3 (v13): out[q,d] = sum_k exp(S[q,k]*SCALE) * V'[k,d].
// Grid (128 qt, 2 b), 512 thr (8 waves), qtile 64, BK 64. R9's 2-barrier
// structure; V' in registers. Iteration t:
//   vmcnt(0) -> barrier            [K(t) staged; P reuse safe via barrier]
//   issue V(t) loads (8 ldg8)      [FIRST: FIFO -> counted wait before PV]
//   issue K(t+1) staging (4 gll)
//   S(t) 16 MFMA; exp -> P LDS; lgkmcnt(0) -> barrier
//   PV(t): pa from LDS, vb = vfr registers (compiler waits vmcnt(4))
// LDS: K dbuf 2x32K @0, P 8K @65536 = 72 KB.
// ---------------------------------------------------------------------------
__global__ __launch_bounds__(512, 1) void k_attn(
    const unsigned short* __restrict__ Qb, const unsigned short* __restrict__ Kb,
    const unsigned short* __restrict__ Vt, float* __restrict__ out)
{
    extern __shared__ char smem[];
    const int qt = blockIdx.x, b = blockIdx.y;
    const int tid = threadIdx.x, w = tid >> 6, lane = tid & 63;
    const int lr = lane & 15, lg = lane >> 4;
    const int qbase = qt * 64;
    const int wqs = w >> 2;          // q strip (32 q)
    const int wks = w & 3;           // S k-quarter (16 k)
    const int wds = w & 3;           // PV d-quarter (64 d)
    const int q0 = wqs * 32;

    // K staging sources, pre-swizzled
    const unsigned short* srcK[4];
#pragma unroll
    for (int i = 0; i < 4; ++i) {
        int L = w * 256 + i * 64 + lane;
        int r = L >> 5, c = (L & 31) ^ (r & 7);
        srcK[i] = Kb + (size_t)(b * N_ + r) * 256 + c * 8;
    }
    // prologue: stage K(0) -> buffer 0
#pragma unroll
    for (int i = 0; i < 4; ++i) {
        gll16(srcK[i], smem + (size_t)(w * 256 + i * 64) * 16);
        srcK[i] += 64 * 256;
    }

    // V' row pointers for this wave's d-quarter
    const unsigned short* vrow[4];
#pragma unroll
    for (int df = 0; df < 4; ++df)
        vrow[df] = Vt + ((size_t)(b * 256 + wds * 64 + df * 16 + lr)) * 8192
                      + lg * 8;

    // hoist Q fragments (32 q x 256 d), pinned
    short8 qfr[2][8];
#pragma unroll
    for (int qf = 0; qf < 2; ++qf) {
        const unsigned short* qrow =
            Qb + (size_t)(b * N_ + qbase + q0 + qf * 16 + lr) * 256;
#pragma unroll
        for (int ks = 0; ks < 8; ++ks) {
            qfr[qf][ks] = ldg8(qrow + ks * 32 + lg * 8);
            PIN8(qfr[qf][ks]);
        }
    }

    f32x4 acco[2][4] = {};

    for (int kt = 0; kt < 128; ++kt) {
        const int cur = kt & 1;
        char* sK = smem + cur * 32768;
        char* sP = smem + 65536;

        WAIT_VM0();                  // K(t) staged (own slices)
        BARRIER();                   // all slices; P reads of t-1 done
        __builtin_amdgcn_sched_barrier(0);

        // V(t) loads FIRST (FIFO: lets the pre-PV wait be counted, not 0)
        short8 vfr[8];
        {
            int kg = kt * 64;
#pragma unroll
            for (int df = 0; df < 4; ++df) {
                vfr[df * 2 + 0] = ldg8(vrow[df] + kg);
                vfr[df * 2 + 1] = ldg8(vrow[df] + kg + 32);
            }
        }

        // stage K(t+1)
        if (kt + 1 < 128) {
            char* nK = smem + (cur ^ 1) * 32768;
#pragma unroll
            for (int i = 0; i < 4; ++i) {
                gll16(srcK[i], nK + (size_t)(w * 256 + i * 64) * 16);
                srcK[i] += 64 * 256;
            }
        }

        // ---- S phase: 32q x 16k ----
        f32x4 sacc[2] = {};
        __builtin_amdgcn_s_setprio(1);
#pragma unroll
        for (int ks = 0; ks < 8; ++ks) {
            int krow = wks * 16 + lr;
            int coff = (ks * 32 + lg * 8) * 2;
            int off = (krow * 512 + coff) ^ ((krow & 7) << 4);
            short8 kb = *reinterpret_cast<const short8*>(sK + off);
            sacc[0] = mfma16(qfr[0][ks], kb, sacc[0]);
            sacc[1] = mfma16(qfr[1][ks], kb, sacc[1]);
        }
        __builtin_amdgcn_s_setprio(0);

        // ---- P = exp(S*SCALE) -> LDS bf16 ----
#pragma unroll
        for (int qf = 0; qf < 2; ++qf)
#pragma unroll
            for (int r = 0; r < 4; ++r) {
                float p = __expf(sacc[qf][r] * SCALE);
                int q = q0 + qf * 16 + lg * 4 + r;
                int kcol = wks * 16 + lr;
                int off = (q * 128 + kcol * 2) ^ ((q & 7) << 4);
                *reinterpret_cast<unsigned short*>(sP + off) = f2bf(p);
            }

        WAIT_LGKM0();                // P writes drained
        BARRIER();
        __builtin_amdgcn_sched_barrier(0);

        // ---- PV phase: 32q x 64d over 64 k (V from registers) ----
        __builtin_amdgcn_s_setprio(1);
#pragma unroll
        for (int kk = 0; kk < 2; ++kk) {
            int coff = (kk * 32 + lg * 8) * 2;
            short8 pa[2];
#pragma unroll
            for (int qf = 0; qf < 2; ++qf) {
                int qq = q0 + qf * 16 + lr;
                int offa = (qq * 128 + coff) ^ ((qq & 7) << 4);
                pa[qf] = *reinterpret_cast<const short8*>(sP + offa);
            }
#pragma unroll
            for (int df = 0; df < 4; ++df) {
                acco[0][df] = mfma16(pa[0], vfr[df * 2 + kk], acco[0][df]);
                acco[1][df] = mfma16(pa[1], vfr[df * 2 + kk], acco[1][df]);
            }
        }
        __builtin_amdgcn_s_setprio(0);
    }

    // epilogue: f32 store
#pragma unroll
    for (int qf = 0; qf < 2; ++qf)
#pragma unroll
        for (int df = 0; df < 4; ++df) {
            int d = wds * 64 + df * 16 + lr;
            int q0r = qbase + q0 + qf * 16 + lg * 4;
#pragma unroll
            for (int r = 0; r < 4; ++r)
                out[(size_t)(b * N_ + q0r + r) * 256 + d] = acco[qf][df][r];
        }
}

extern "C" void kernel_launch(void* const* d_in, const int* in_sizes, int n_in,
                              void* d_out, int out_size, void* d_ws, size_t ws_size,
                              hipStream_t stream)
{
    const float* x  = (const float*)d_in[0];
    const float* Wq = (const float*)d_in[1];
    const float* Wk = (const float*)d_in[2];
    const float* Wv = (const float*)d_in[3];

    char* ws = (char*)d_ws;
    unsigned short* Qb = (unsigned short*)(ws);              //  8 MB
    unsigned short* Kb = (unsigned short*)(ws + 8388608);    //  8 MB
    unsigned short* Vt = (unsigned short*)(ws + 16777216);   //  8 MB
    unsigned short* Wb = (unsigned short*)(ws + 25165824);   // 384 KB
    float* out = (float*)d_out;

    k_cvtw<<<dim3(96), dim3(256), 0, stream>>>(Wq, Wk, Wv, Wb);
    k_proj<<<dim3(256), dim3(512), 0, stream>>>(x, Wb, Qb, Kb, Vt);

    hipFuncSetAttribute((const void*)k_zv,
                        hipFuncAttributeMaxDynamicSharedMemorySize, 131072);
    k_zv<<<dim3(128, 2), dim3(512), 131072, stream>>>(Qb, Kb, Vt);

    hipFuncSetAttribute((const void*)k_attn,
                        hipFuncAttributeMaxDynamicSharedMemorySize, 73728);
    k_attn<<<dim3(128, 2), dim3(512), 73728, stream>>>(Qb, Kb, Vt, out);
}

// Round 14
// 300.788 us; speedup vs baseline: 1.4941x; 1.3702x over previous
//
#include <hip/hip_runtime.h>
#include <hip/hip_bf16.h>

// Attention with softmax over the QUERY axis (axis=1):
//   attn[:,q,k] = exp(S[q,k]) / Z[k],  Z[k] = sum_q exp(S[q,k])
//   out = expS @ (diag(1/Z) V)   -- 1/Z folded into V by k_zv's epilogue.
// B=2, N=8192, D=256. All matmuls via mfma_f32_16x16x32_bf16.
// R14: k_attn REVERTED to the proven R9/R10 221us structure (V-from-global
// refuted 3x: transposed-V per-lane reads are uncoalesced, 16 lines/instr).
// k_proj v3: Wb streamed through LDS (gll dbuf, pre-swizzled source, the
// k_zv-proven pattern) -- v2's Wb reads had the same uncoalesced pattern.

#define N_ 8192
#define SCALE 0.0625f

typedef __attribute__((ext_vector_type(8))) short short8;
typedef __attribute__((ext_vector_type(4))) float f32x4;
typedef __attribute__((ext_vector_type(4))) unsigned short ushort4_t;

__device__ inline unsigned short f2bf(float f) {
    unsigned int x = __float_as_uint(f);
    unsigned int r = (x + 0x7fffu + ((x >> 16) & 1u)) >> 16;  // RNE
    return (unsigned short)r;
}

__device__ inline short8 ldg8(const unsigned short* p) {
    return *reinterpret_cast<const short8*>(p);
}

__device__ inline short8 cvt8(const float* p) {
    float4 a = *(const float4*)p;
    float4 b = *(const float4*)(p + 4);
    short8 r;
    r[0] = (short)f2bf(a.x); r[1] = (short)f2bf(a.y);
    r[2] = (short)f2bf(a.z); r[3] = (short)f2bf(a.w);
    r[4] = (short)f2bf(b.x); r[5] = (short)f2bf(b.y);
    r[6] = (short)f2bf(b.z); r[7] = (short)f2bf(b.w);
    return r;
}

__device__ inline f32x4 mfma16(short8 a, short8 b, f32x4 c) {
    return __builtin_amdgcn_mfma_f32_16x16x32_bf16(a, b, c, 0, 0, 0);
}

__device__ inline float bf2f(unsigned short u) {
    return __uint_as_float(((unsigned)u) << 16);
}

#define PIN8(v) asm volatile("" : "+v"(v))

typedef __attribute__((address_space(3))) unsigned int lds_u32;
typedef __attribute__((address_space(1))) const unsigned int glb_u32;
__device__ __forceinline__ void gll16(const void* g, void* l) {
    __builtin_amdgcn_global_load_lds((glb_u32*)g, (lds_u32*)l, 16, 0, 0);
}
#define WAIT_VM0()   asm volatile("s_waitcnt vmcnt(0)" ::: "memory")
#define WAIT_LGKM0() asm volatile("s_waitcnt lgkmcnt(0)" ::: "memory")
#define BARRIER()    __builtin_amdgcn_s_barrier()

// ---------------------------------------------------------------------------
// Kernel 0: W (3 x 256x256 f32) -> Wb (768x256 bf16), concatenated Q|K|V.
// ---------------------------------------------------------------------------
__global__ __launch_bounds__(256) void k_cvtw(
    const float* __restrict__ Wq, const float* __restrict__ Wk,
    const float* __restrict__ Wv, unsigned short* __restrict__ Wb)
{
    int t = blockIdx.x * 256 + threadIdx.x;
    int e8 = t * 8;
    const float* src = (e8 < 65536) ? Wq + e8
                     : (e8 < 131072) ? Wk + (e8 - 65536)
                                     : Wv + (e8 - 131072);
    *reinterpret_cast<short8*>(Wb + e8) = cvt8(src);
}

// ---------------------------------------------------------------------------
// Kernel 1 (v3): QKV projection. Grid 256 blocks (64 x-rows each), 512 thr.
// x-tile 64x256 bf16 in LDS (swizzled, converted once); x-frags hoisted to
// regs (pinned). Wb streamed in 12 chunks of 64 e-rows via gll dbuf
// (pre-swizzled source, 1 barrier/chunk). Waves: 2 q-strips x 4 e-quarters.
// Chunk c: e-rows c*64..+64; mat = c>>2 (0:Q 1:K 2:V) -- never crosses.
// LDS: sX 32KB @0, sW dbuf 2x32KB @32768 = 96 KB.
// ---------------------------------------------------------------------------
__global__ __launch_bounds__(512, 1) void k_proj(
    const float* __restrict__ x, const unsigned short* __restrict__ Wb,
    unsigned short* __restrict__ Qb, unsigned short* __restrict__ Kb,
    unsigned short* __restrict__ Vt)
{
    extern __shared__ char smem[];
    unsigned short* sX = (unsigned short*)smem;        // 32 KB
    char* sW = smem + 32768;                           // 2 x 32 KB
    const int rb = blockIdx.x;
    const int tid = threadIdx.x, w = tid >> 6, lane = tid & 63;
    const int lr = lane & 15, lg = lane >> 4;
    const int wqs = w >> 2, wes = w & 3;

    // staging offsets for one 64x256 bf16 tile (2048 granules of 16B)
    int eoff[4], doff[4];
#pragma unroll
    for (int i = 0; i < 4; ++i) {
        int L = tid + i * 512;
        int r = L >> 5, c = (L & 31) ^ (r & 7);
        eoff[i] = r * 256 + c * 8;           // source element offset
        doff[i] = L * 16;                    // linear LDS byte offset
    }

    // prologue: stage Wb chunk 0 (async) + convert/stage x-tile
    const unsigned short* wsrc = Wb;
#pragma unroll
    for (int i = 0; i < 4; ++i)
        gll16(wsrc + eoff[i], sW + doff[i]);

#pragma unroll
    for (int i = 0; i < 4; ++i) {
        int g = tid + i * 512;
        int r = g >> 5, c = g & 31;
        int off = (r * 512 + c * 16) ^ ((r & 7) << 4);
        *reinterpret_cast<short8*>(reinterpret_cast<char*>(sX) + off) =
            cvt8(x + (size_t)(rb * 64 + r) * 256 + c * 8);
    }
    __syncthreads();

    // hoist x fragments: 32 rows (2 frags) x 8 d-slices, pinned (64 VGPR)
    short8 xf[2][8];
#pragma unroll
    for (int qf = 0; qf < 2; ++qf)
#pragma unroll
        for (int ks = 0; ks < 8; ++ks) {
            int row = wqs * 32 + qf * 16 + lr;
            int off = (row * 512 + (ks * 32 + lg * 8) * 2) ^ ((row & 7) << 4);
            xf[qf][ks] = *reinterpret_cast<const short8*>(
                reinterpret_cast<const char*>(sX) + off);
            PIN8(xf[qf][ks]);
        }

    for (int c = 0; c < 12; ++c) {
        const int cur = c & 1;
        const char* sWc = sW + cur * 32768;

        WAIT_VM0();                  // chunk c staged (own ops)
        BARRIER();                   // all slices; prev chunk's reads done
        __builtin_amdgcn_sched_barrier(0);

        if (c + 1 < 12) {
            const unsigned short* wn = Wb + (size_t)(c + 1) * 64 * 256;
            char* nW = sW + (cur ^ 1) * 32768;
#pragma unroll
            for (int i = 0; i < 4; ++i)
                gll16(wn + eoff[i], nW + doff[i]);
        }

        f32x4 acc[2] = {};
#pragma unroll
        for (int ks = 0; ks < 8; ++ks) {
            int row = wes * 16 + lr;
            int off = (row * 512 + (ks * 32 + lg * 8) * 2) ^ ((row & 7) << 4);
            short8 wf = *reinterpret_cast<const short8*>(sWc + off);
            acc[0] = mfma16(xf[0][ks], wf, acc[0]);
            acc[1] = mfma16(xf[1][ks], wf, acc[1]);
        }

        // write out: e-cols c*64 + wes*16 + lr within matrix (c&3)*64 ...
        int mat = c >> 2;                     // chunk-uniform
        int ecol = (c & 3) * 64 + wes * 16 + lr;
#pragma unroll
        for (int qf = 0; qf < 2; ++qf) {
            int rbase = rb * 64 + wqs * 32 + qf * 16 + lg * 4;
            if (mat < 2) {
                unsigned short* dst = (mat == 0) ? Qb : Kb;
#pragma unroll
                for (int r = 0; r < 4; ++r)
                    dst[(size_t)(rbase + r) * 256 + ecol] = f2bf(acc[qf][r]);
            } else {
                int bidx = rbase >> 13, nr = rbase & 8191;
                ushort4_t v;
#pragma unroll
                for (int r = 0; r < 4; ++r) v[r] = f2bf(acc[qf][r]);
                *reinterpret_cast<ushort4_t*>(
                    Vt + ((size_t)bidx * 256 + ecol) * 8192 + nr) = v;
            }
        }
    }
}

// ---------------------------------------------------------------------------
// Kernel 2 (k_zv): per (kt,b): Z[k] = sum_q exp(S[q,k]*SCALE), then
// Vt[b][:, kt*64..+64] *= 1/Z in place. (Proven R10, ~55us.)
// ---------------------------------------------------------------------------
__global__ __launch_bounds__(512, 1) void k_zv(
    const unsigned short* __restrict__ Qb, const unsigned short* __restrict__ Kb,
    unsigned short* __restrict__ Vt)
{
    extern __shared__ char smem[];            // Q dbuf: 2 x 65536 B
    __shared__ float zred[8][32];
    __shared__ float zfin[64];
    const int kt = blockIdx.x, b = blockIdx.y;
    const int tid = threadIdx.x, w = tid >> 6, lane = tid & 63;
    const int lr = lane & 15, lg = lane >> 4;
    const int qs = w & 3, kh = w >> 2;

    short8 kfr[2][8];
#pragma unroll
    for (int kn = 0; kn < 2; ++kn)
#pragma unroll
        for (int ks = 0; ks < 8; ++ks) {
            kfr[kn][ks] = ldg8(
                Kb + (size_t)(b * N_ + kt * 64 + kh * 32 + kn * 16 + lr) * 256
                   + ks * 32 + lg * 8);
            PIN8(kfr[kn][ks]);
        }

    int eoff[8], doff[8];
#pragma unroll
    for (int i = 0; i < 8; ++i) {
        int L = i * 512 + w * 64 + lane;
        int r = L >> 5, c = (L & 31) ^ (r & 7);
        eoff[i] = r * 256 + c * 8;
        doff[i] = L * 16;
    }
    const unsigned short* qbase = Qb + (size_t)b * N_ * 256;

#pragma unroll
    for (int i = 0; i < 8; ++i)
        gll16(qbase + eoff[i], smem + doff[i]);

    float zs0 = 0.f, zs1 = 0.f;
    for (int it = 0; it < 64; ++it) {
        const int cur = it & 1;
        const char* sQ = smem + cur * 65536;

        WAIT_VM0();
        BARRIER();
        __builtin_amdgcn_sched_barrier(0);

        if (it + 1 < 64) {
            const unsigned short* qsrc = qbase + (size_t)(it + 1) * 128 * 256;
            char* nQ = smem + (cur ^ 1) * 65536;
#pragma unroll
            for (int i = 0; i < 8; ++i)
                gll16(qsrc + eoff[i], nQ + doff[i]);
        }

        f32x4 acc[2][2] = {};
        __builtin_amdgcn_s_setprio(1);
#pragma unroll
        for (int ks = 0; ks < 8; ++ks) {
            int coff = (ks * 32 + lg * 8) * 2;
#pragma unroll
            for (int qf = 0; qf < 2; ++qf) {
                int row = qs * 32 + qf * 16 + lr;
                int off = (row * 512 + coff) ^ ((row & 7) << 4);
                short8 qa = *reinterpret_cast<const short8*>(sQ + off);
                acc[qf][0] = mfma16(qa, kfr[0][ks], acc[qf][0]);
                acc[qf][1] = mfma16(qa, kfr[1][ks], acc[qf][1]);
            }
        }
        __builtin_amdgcn_s_setprio(0);

#pragma unroll
        for (int qf = 0; qf < 2; ++qf)
#pragma unroll
            for (int r = 0; r < 4; ++r) {
                zs0 += __expf(acc[qf][0][r] * SCALE);
                zs1 += __expf(acc[qf][1][r] * SCALE);
            }
    }

    zs0 += __shfl_xor(zs0, 16); zs0 += __shfl_xor(zs0, 32);
    zs1 += __shfl_xor(zs1, 16); zs1 += __shfl_xor(zs1, 32);
    if (lg == 0) {
        zred[w][lr]      = zs0;
        zred[w][16 + lr] = zs1;
    }
    __syncthreads();
    if (tid < 64) {
        int kh2 = tid >> 5, kc = tid & 31;
        float z = zred[kh2 * 4 + 0][kc] + zred[kh2 * 4 + 1][kc] +
                  zred[kh2 * 4 + 2][kc] + zred[kh2 * 4 + 3][kc];
        zfin[tid] = 1.0f / z;
    }
    __syncthreads();

#pragma unroll
    for (int i = 0; i < 4; ++i) {
        int G = i * 512 + tid;
        int d = G >> 3, c = G & 7;
        unsigned short* p =
            Vt + ((size_t)b * 256 + d) * 8192 + kt * 64 + c * 8;
        short8 v = *reinterpret_cast<short8*>(p);
        short8 o;
#pragma unroll
        for (int j = 0; j < 8; ++j)
            o[j] = (short)f2bf(bf2f((unsigned short)v[j]) * zfin[c * 8 + j]);
        *reinterpret_cast<short8*>(p) = o;
    }
}

// ---------------------------------------------------------------------------
// Kernel 3: out[q,d] = sum_k exp(S[q,k]*SCALE) * V'[k,d].
// Proven R9/R10 structure (221us): grid (128 qt, 2 b), 512 thr, qtile 64,
// BK 64, K/V dbuf via global_load_lds, P via LDS, 2 barriers per kt.
// LDS: K dbuf 2x32K @0, V dbuf 2x32K @65536, P 8K @131072 = 136 KB.
// ---------------------------------------------------------------------------
__global__ __launch_bounds__(512, 1) void k_attn(
    const unsigned short* __restrict__ Qb, const unsigned short* __restrict__ Kb,
    const unsigned short* __restrict__ Vt, float* __restrict__ out)
{
    extern __shared__ char smem[];
    const int qt = blockIdx.x, b = blockIdx.y;
    const int tid = threadIdx.x, w = tid >> 6, lane = tid & 63;
    const int lr = lane & 15, lg = lane >> 4;
    const int qbase = qt * 64;
    const int wqs = w >> 2;
    const int wks = w & 3;
    const int wds = w & 3;
    const int q0 = wqs * 32;

    const unsigned short* srcK[4];
    const unsigned short* srcV[4];
#pragma unroll
    for (int i = 0; i < 4; ++i) {
        int L = w * 256 + i * 64 + lane;
        int r = L >> 5, c = (L & 31) ^ (r & 7);
        srcK[i] = Kb + (size_t)(b * N_ + r) * 256 + c * 8;
        int d = L >> 3, c2 = (L & 7) ^ (d & 7);
        srcV[i] = Vt + ((size_t)b * 256 + d) * 8192 + c2 * 8;
    }

#pragma unroll
    for (int i = 0; i < 4; ++i) {
        gll16(srcK[i], smem + (size_t)(w * 256 + i * 64) * 16);
        gll16(srcV[i], smem + 65536 + (size_t)(w * 256 + i * 64) * 16);
        srcK[i] += 64 * 256;
        srcV[i] += 64;
    }

    short8 qfr[2][8];
#pragma unroll
    for (int qf = 0; qf < 2; ++qf) {
        const unsigned short* qrow =
            Qb + (size_t)(b * N_ + qbase + q0 + qf * 16 + lr) * 256;
#pragma unroll
        for (int ks = 0; ks < 8; ++ks) {
            qfr[qf][ks] = ldg8(qrow + ks * 32 + lg * 8);
            PIN8(qfr[qf][ks]);
        }
    }

    f32x4 acco[2][4] = {};

    for (int kt = 0; kt < 128; ++kt) {
        const int cur = kt & 1;
        char* sK = smem + cur * 32768;
        char* sV = smem + 65536 + cur * 32768;
        char* sP = smem + 131072;

        WAIT_VM0();
        BARRIER();
        __builtin_amdgcn_sched_barrier(0);

        if (kt + 1 < 128) {
            char* nK = smem + (cur ^ 1) * 32768;
            char* nV = smem + 65536 + (cur ^ 1) * 32768;
#pragma unroll
            for (int i = 0; i < 4; ++i) {
                gll16(srcK[i], nK + (size_t)(w * 256 + i * 64) * 16);
                gll16(srcV[i], nV + (size_t)(w * 256 + i * 64) * 16);
                srcK[i] += 64 * 256;
                srcV[i] += 64;
            }
        }

        // ---- S phase: 32q x 16k ----
        f32x4 sacc[2] = {};
        __builtin_amdgcn_s_setprio(1);
#pragma unroll
        for (int ks = 0; ks < 8; ++ks) {
            int krow = wks * 16 + lr;
            int coff = (ks * 32 + lg * 8) * 2;
            int off = (krow * 512 + coff) ^ ((krow & 7) << 4);
            short8 kb = *reinterpret_cast<const short8*>(sK + off);
            sacc[0] = mfma16(qfr[0][ks], kb, sacc[0]);
            sacc[1] = mfma16(qfr[1][ks], kb, sacc[1]);
        }
        __builtin_amdgcn_s_setprio(0);

        // ---- P = exp(S*SCALE) -> LDS bf16 ----
#pragma unroll
        for (int qf = 0; qf < 2; ++qf)
#pragma unroll
            for (int r = 0; r < 4; ++r) {
                float p = __expf(sacc[qf][r] * SCALE);
                int q = q0 + qf * 16 + lg * 4 + r;
                int kcol = wks * 16 + lr;
                int off = (q * 128 + kcol * 2) ^ ((q & 7) << 4);
                *reinterpret_cast<unsigned short*>(sP + off) = f2bf(p);
            }

        WAIT_LGKM0();
        BARRIER();
        __builtin_amdgcn_sched_barrier(0);

        // ---- PV phase: 32q x 64d over 64 k ----
        __builtin_amdgcn_s_setprio(1);
#pragma unroll
        for (int kk = 0; kk < 2; ++kk) {
            int coff = (kk * 32 + lg * 8) * 2;
            short8 pa[2];
#pragma unroll
            for (int qf = 0; qf < 2; ++qf) {
                int qq = q0 + qf * 16 + lr;
                int offa = (qq * 128 + coff) ^ ((qq & 7) << 4);
                pa[qf] = *reinterpret_cast<const short8*>(sP + offa);
            }
#pragma unroll
            for (int df = 0; df < 4; ++df) {
                int d = wds * 64 + df * 16 + lr;
                int offb = (d * 128 + coff) ^ ((d & 7) << 4);
                short8 vb = *reinterpret_cast<const short8*>(sV + offb);
                acco[0][df] = mfma16(pa[0], vb, acco[0][df]);
                acco[1][df] = mfma16(pa[1], vb, acco[1][df]);
            }
        }
        __builtin_amdgcn_s_setprio(0);
    }

    // epilogue: f32 store
#pragma unroll
    for (int qf = 0; qf < 2; ++qf)
#pragma unroll
        for (int df = 0; df < 4; ++df) {
            int d = wds * 64 + df * 16 + lr;
            int q0r = qbase + q0 + qf * 16 + lg * 4;
#pragma unroll
            for (int r = 0; r < 4; ++r)
                out[(size_t)(b * N_ + q0r + r) * 256 + d] = acco[qf][df][r];
        }
}

extern "C" void kernel_launch(void* const* d_in, const int* in_sizes, int n_in,
                              void* d_out, int out_size, void* d_ws, size_t ws_size,
                              hipStream_t stream)
{
    const float* x  = (const float*)d_in[0];
    const float* Wq = (const float*)d_in[1];
    const float* Wk = (const float*)d_in[2];
    const float* Wv = (const float*)d_in[3];

    char* ws = (char*)d_ws;
    unsigned short* Qb = (unsigned short*)(ws);              //  8 MB
    unsigned short* Kb = (unsigned short*)(ws + 8388608);    //  8 MB
    unsigned short* Vt = (unsigned short*)(ws + 16777216);   //  8 MB
    unsigned short* Wb = (unsigned short*)(ws + 25165824);   // 384 KB
    float* out = (float*)d_out;

    k_cvtw<<<dim3(96), dim3(256), 0, stream>>>(Wq, Wk, Wv, Wb);

    hipFuncSetAttribute((const void*)k_proj,
                        hipFuncAttributeMaxDynamicSharedMemorySize, 98304);
    k_proj<<<dim3(256), dim3(512), 98304, stream>>>(x, Wb, Qb, Kb, Vt);

    hipFuncSetAttribute((const void*)k_zv,
                        hipFuncAttributeMaxDynamicSharedMemorySize, 131072);
    k_zv<<<dim3(128, 2), dim3(512), 131072, stream>>>(Qb, Kb, Vt);

    hipFuncSetAttribute((const void*)k_attn,
                        hipFuncAttributeMaxDynamicSharedMemorySize, 139264);
    k_attn<<<dim3(128, 2), dim3(512), 139264, stream>>>(Qb, Kb, Vt, out);
}

// Round 15
// 253.826 us; speedup vs baseline: 1.7706x; 1.1850x over previous
//
#include <hip/hip_runtime.h>
#include <hip/hip_bf16.h>

// Attention with softmax over the QUERY axis (axis=1):
//   attn[:,q,k] = exp(S[q,k]) / Z[k],  Z[k] = sum_q exp(S[q,k])
//   out = expS @ (diag(1/Z) V)   -- 1/Z folded into V by k_zv's epilogue.
// B=2, N=8192, D=256. All matmuls via mfma_f32_16x16x32_bf16.
// R15: k_attn qtile 128 with the PROVEN 32q-per-wave shape (R4's qtile-128
// used 64q/wave -> qfr 128 VGPR -> spill; this keeps qfr at 64 VGPR).
// 8 waves = 4 q-strips x 2 k-halves (S) / 2 d-halves (PV). Same 2-barrier
// template as R9/R14. k-range split across 2 blocks (grid 64x2x2), k_add merge.
// pa-reads and barrier slack amortize over 2x q -> predicted ~150us.

#define N_ 8192
#define SCALE 0.0625f

typedef __attribute__((ext_vector_type(8))) short short8;
typedef __attribute__((ext_vector_type(4))) float f32x4;
typedef __attribute__((ext_vector_type(4))) unsigned short ushort4_t;

__device__ inline unsigned short f2bf(float f) {
    unsigned int x = __float_as_uint(f);
    unsigned int r = (x + 0x7fffu + ((x >> 16) & 1u)) >> 16;  // RNE
    return (unsigned short)r;
}

__device__ inline short8 ldg8(const unsigned short* p) {
    return *reinterpret_cast<const short8*>(p);
}

__device__ inline short8 cvt8(const float* p) {
    float4 a = *(const float4*)p;
    float4 b = *(const float4*)(p + 4);
    short8 r;
    r[0] = (short)f2bf(a.x); r[1] = (short)f2bf(a.y);
    r[2] = (short)f2bf(a.z); r[3] = (short)f2bf(a.w);
    r[4] = (short)f2bf(b.x); r[5] = (short)f2bf(b.y);
    r[6] = (short)f2bf(b.z); r[7] = (short)f2bf(b.w);
    return r;
}

__device__ inline f32x4 mfma16(short8 a, short8 b, f32x4 c) {
    return __builtin_amdgcn_mfma_f32_16x16x32_bf16(a, b, c, 0, 0, 0);
}

__device__ inline float bf2f(unsigned short u) {
    return __uint_as_float(((unsigned)u) << 16);
}

#define PIN8(v) asm volatile("" : "+v"(v))

typedef __attribute__((address_space(3))) unsigned int lds_u32;
typedef __attribute__((address_space(1))) const unsigned int glb_u32;
__device__ __forceinline__ void gll16(const void* g, void* l) {
    __builtin_amdgcn_global_load_lds((glb_u32*)g, (lds_u32*)l, 16, 0, 0);
}
#define WAIT_VM0()   asm volatile("s_waitcnt vmcnt(0)" ::: "memory")
#define WAIT_LGKM0() asm volatile("s_waitcnt lgkmcnt(0)" ::: "memory")
#define BARRIER()    __builtin_amdgcn_s_barrier()

// ---------------------------------------------------------------------------
// Kernel 0: W (3 x 256x256 f32) -> Wb (768x256 bf16), concatenated Q|K|V.
// ---------------------------------------------------------------------------
__global__ __launch_bounds__(256) void k_cvtw(
    const float* __restrict__ Wq, const float* __restrict__ Wk,
    const float* __restrict__ Wv, unsigned short* __restrict__ Wb)
{
    int t = blockIdx.x * 256 + threadIdx.x;
    int e8 = t * 8;
    const float* src = (e8 < 65536) ? Wq + e8
                     : (e8 < 131072) ? Wk + (e8 - 65536)
                                     : Wv + (e8 - 131072);
    *reinterpret_cast<short8*>(Wb + e8) = cvt8(src);
}

// ---------------------------------------------------------------------------
// Kernel 1 (v3): QKV projection (proven R14).
// ---------------------------------------------------------------------------
__global__ __launch_bounds__(512, 1) void k_proj(
    const float* __restrict__ x, const unsigned short* __restrict__ Wb,
    unsigned short* __restrict__ Qb, unsigned short* __restrict__ Kb,
    unsigned short* __restrict__ Vt)
{
    extern __shared__ char smem[];
    unsigned short* sX = (unsigned short*)smem;        // 32 KB
    char* sW = smem + 32768;                           // 2 x 32 KB
    const int rb = blockIdx.x;
    const int tid = threadIdx.x, w = tid >> 6, lane = tid & 63;
    const int lr = lane & 15, lg = lane >> 4;
    const int wqs = w >> 2, wes = w & 3;

    int eoff[4], doff[4];
#pragma unroll
    for (int i = 0; i < 4; ++i) {
        int L = tid + i * 512;
        int r = L >> 5, c = (L & 31) ^ (r & 7);
        eoff[i] = r * 256 + c * 8;
        doff[i] = L * 16;
    }

    const unsigned short* wsrc = Wb;
#pragma unroll
    for (int i = 0; i < 4; ++i)
        gll16(wsrc + eoff[i], sW + doff[i]);

#pragma unroll
    for (int i = 0; i < 4; ++i) {
        int g = tid + i * 512;
        int r = g >> 5, c = g & 31;
        int off = (r * 512 + c * 16) ^ ((r & 7) << 4);
        *reinterpret_cast<short8*>(reinterpret_cast<char*>(sX) + off) =
            cvt8(x + (size_t)(rb * 64 + r) * 256 + c * 8);
    }
    __syncthreads();

    short8 xf[2][8];
#pragma unroll
    for (int qf = 0; qf < 2; ++qf)
#pragma unroll
        for (int ks = 0; ks < 8; ++ks) {
            int row = wqs * 32 + qf * 16 + lr;
            int off = (row * 512 + (ks * 32 + lg * 8) * 2) ^ ((row & 7) << 4);
            xf[qf][ks] = *reinterpret_cast<const short8*>(
                reinterpret_cast<const char*>(sX) + off);
            PIN8(xf[qf][ks]);
        }

    for (int c = 0; c < 12; ++c) {
        const int cur = c & 1;
        const char* sWc = sW + cur * 32768;

        WAIT_VM0();
        BARRIER();
        __builtin_amdgcn_sched_barrier(0);

        if (c + 1 < 12) {
            const unsigned short* wn = Wb + (size_t)(c + 1) * 64 * 256;
            char* nW = sW + (cur ^ 1) * 32768;
#pragma unroll
            for (int i = 0; i < 4; ++i)
                gll16(wn + eoff[i], nW + doff[i]);
        }

        f32x4 acc[2] = {};
#pragma unroll
        for (int ks = 0; ks < 8; ++ks) {
            int row = wes * 16 + lr;
            int off = (row * 512 + (ks * 32 + lg * 8) * 2) ^ ((row & 7) << 4);
            short8 wf = *reinterpret_cast<const short8*>(sWc + off);
            acc[0] = mfma16(xf[0][ks], wf, acc[0]);
            acc[1] = mfma16(xf[1][ks], wf, acc[1]);
        }

        int mat = c >> 2;
        int ecol = (c & 3) * 64 + wes * 16 + lr;
#pragma unroll
        for (int qf = 0; qf < 2; ++qf) {
            int rbase = rb * 64 + wqs * 32 + qf * 16 + lg * 4;
            if (mat < 2) {
                unsigned short* dst = (mat == 0) ? Qb : Kb;
#pragma unroll
                for (int r = 0; r < 4; ++r)
                    dst[(size_t)(rbase + r) * 256 + ecol] = f2bf(acc[qf][r]);
            } else {
                int bidx = rbase >> 13, nr = rbase & 8191;
                ushort4_t v;
#pragma unroll
                for (int r = 0; r < 4; ++r) v[r] = f2bf(acc[qf][r]);
                *reinterpret_cast<ushort4_t*>(
                    Vt + ((size_t)bidx * 256 + ecol) * 8192 + nr) = v;
            }
        }
    }
}

// ---------------------------------------------------------------------------
// Kernel 2 (k_zv): per (kt,b): Z[k] = sum_q exp(S[q,k]*SCALE), then
// Vt[b][:, kt*64..+64] *= 1/Z in place. (Proven R10, ~55us.)
// ---------------------------------------------------------------------------
__global__ __launch_bounds__(512, 1) void k_zv(
    const unsigned short* __restrict__ Qb, const unsigned short* __restrict__ Kb,
    unsigned short* __restrict__ Vt)
{
    extern __shared__ char smem[];            // Q dbuf: 2 x 65536 B
    __shared__ float zred[8][32];
    __shared__ float zfin[64];
    const int kt = blockIdx.x, b = blockIdx.y;
    const int tid = threadIdx.x, w = tid >> 6, lane = tid & 63;
    const int lr = lane & 15, lg = lane >> 4;
    const int qs = w & 3, kh = w >> 2;

    short8 kfr[2][8];
#pragma unroll
    for (int kn = 0; kn < 2; ++kn)
#pragma unroll
        for (int ks = 0; ks < 8; ++ks) {
            kfr[kn][ks] = ldg8(
                Kb + (size_t)(b * N_ + kt * 64 + kh * 32 + kn * 16 + lr) * 256
                   + ks * 32 + lg * 8);
            PIN8(kfr[kn][ks]);
        }

    int eoff[8], doff[8];
#pragma unroll
    for (int i = 0; i < 8; ++i) {
        int L = i * 512 + w * 64 + lane;
        int r = L >> 5, c = (L & 31) ^ (r & 7);
        eoff[i] = r * 256 + c * 8;
        doff[i] = L * 16;
    }
    const unsigned short* qbase = Qb + (size_t)b * N_ * 256;

#pragma unroll
    for (int i = 0; i < 8; ++i)
        gll16(qbase + eoff[i], smem + doff[i]);

    float zs0 = 0.f, zs1 = 0.f;
    for (int it = 0; it < 64; ++it) {
        const int cur = it & 1;
        const char* sQ = smem + cur * 65536;

        WAIT_VM0();
        BARRIER();
        __builtin_amdgcn_sched_barrier(0);

        if (it + 1 < 64) {
            const unsigned short* qsrc = qbase + (size_t)(it + 1) * 128 * 256;
            char* nQ = smem + (cur ^ 1) * 65536;
#pragma unroll
            for (int i = 0; i < 8; ++i)
                gll16(qsrc + eoff[i], nQ + doff[i]);
        }

        f32x4 acc[2][2] = {};
        __builtin_amdgcn_s_setprio(1);
#pragma unroll
        for (int ks = 0; ks < 8; ++ks) {
            int coff = (ks * 32 + lg * 8) * 2;
#pragma unroll
            for (int qf = 0; qf < 2; ++qf) {
                int row = qs * 32 + qf * 16 + lr;
                int off = (row * 512 + coff) ^ ((row & 7) << 4);
                short8 qa = *reinterpret_cast<const short8*>(sQ + off);
                acc[qf][0] = mfma16(qa, kfr[0][ks], acc[qf][0]);
                acc[qf][1] = mfma16(qa, kfr[1][ks], acc[qf][1]);
            }
        }
        __builtin_amdgcn_s_setprio(0);

#pragma unroll
        for (int qf = 0; qf < 2; ++qf)
#pragma unroll
            for (int r = 0; r < 4; ++r) {
                zs0 += __expf(acc[qf][0][r] * SCALE);
                zs1 += __expf(acc[qf][1][r] * SCALE);
            }
    }

    zs0 += __shfl_xor(zs0, 16); zs0 += __shfl_xor(zs0, 32);
    zs1 += __shfl_xor(zs1, 16); zs1 += __shfl_xor(zs1, 32);
    if (lg == 0) {
        zred[w][lr]      = zs0;
        zred[w][16 + lr] = zs1;
    }
    __syncthreads();
    if (tid < 64) {
        int kh2 = tid >> 5, kc = tid & 31;
        float z = zred[kh2 * 4 + 0][kc] + zred[kh2 * 4 + 1][kc] +
                  zred[kh2 * 4 + 2][kc] + zred[kh2 * 4 + 3][kc];
        zfin[tid] = 1.0f / z;
    }
    __syncthreads();

#pragma unroll
    for (int i = 0; i < 4; ++i) {
        int G = i * 512 + tid;
        int d = G >> 3, c = G & 7;
        unsigned short* p =
            Vt + ((size_t)b * 256 + d) * 8192 + kt * 64 + c * 8;
        short8 v = *reinterpret_cast<short8*>(p);
        short8 o;
#pragma unroll
        for (int j = 0; j < 8; ++j)
            o[j] = (short)f2bf(bf2f((unsigned short)v[j]) * zfin[c * 8 + j]);
        *reinterpret_cast<short8*>(p) = o;
    }
}

// ---------------------------------------------------------------------------
// Kernel 3 (v15): out[q,d] = sum_k exp(S[q,k]*SCALE) * V'[k,d].
// Grid (64 qt, NKH, 2 b), 512 thr (8 waves). qtile 128, BK 64, nkt tiles/blk.
// Waves: wqs=w>>1 (4 strips of 32q); wkh=w&1 (S k-half, 32k);
//        wds=w&1 (PV d-half, 128d). Per wave: S 32q x 32k (sacc[2][2]),
// PV 32q x 128d (acco[2][8], AGPR). qfr 64 VGPR (the R9 profile - no spill).
// Same 2-barrier template as R9/R14.
// LDS: K dbuf 2x32K @0, V dbuf 2x32K @65536, P 16K @131072 = 144 KB.
// ---------------------------------------------------------------------------
__global__ __launch_bounds__(512, 1) void k_attn(
    const unsigned short* __restrict__ Qb, const unsigned short* __restrict__ Kb,
    const unsigned short* __restrict__ Vt, float* __restrict__ out,
    float* __restrict__ part, int nkt)
{
    extern __shared__ char smem[];
    const int qt = blockIdx.x, kh = blockIdx.y, b = blockIdx.z;
    const int tid = threadIdx.x, w = tid >> 6, lane = tid & 63;
    const int lr = lane & 15, lg = lane >> 4;
    const int qbase = qt * 128;
    const int wqs = w >> 1;          // q strip (32 q)
    const int wkh = w & 1;           // S k-half (32 k)
    const int wds = w & 1;           // PV d-half (128 d)
    const int q0 = wqs * 32;
    const int k0 = kh * nkt * 64;

    // staging sources, pre-swizzled (identical pattern to R9/R14)
    const unsigned short* srcK[4];
    const unsigned short* srcV[4];
#pragma unroll
    for (int i = 0; i < 4; ++i) {
        int L = w * 256 + i * 64 + lane;
        int r = L >> 5, c = (L & 31) ^ (r & 7);
        srcK[i] = Kb + (size_t)(b * N_ + k0 + r) * 256 + c * 8;
        int d = L >> 3, c2 = (L & 7) ^ (d & 7);
        srcV[i] = Vt + ((size_t)b * 256 + d) * 8192 + k0 + c2 * 8;
    }

    // prologue: stage tile 0 into buffer 0 (async)
#pragma unroll
    for (int i = 0; i < 4; ++i) {
        gll16(srcK[i], smem + (size_t)(w * 256 + i * 64) * 16);
        gll16(srcV[i], smem + 65536 + (size_t)(w * 256 + i * 64) * 16);
        srcK[i] += 64 * 256;
        srcV[i] += 64;
    }

    // hoist Q fragments: 32 rows (2 frags) x 8 d-slices, PINNED (64 VGPR)
    short8 qfr[2][8];
#pragma unroll
    for (int qf = 0; qf < 2; ++qf) {
        const unsigned short* qrow =
            Qb + (size_t)(b * N_ + qbase + q0 + qf * 16 + lr) * 256;
#pragma unroll
        for (int ks = 0; ks < 8; ++ks) {
            qfr[qf][ks] = ldg8(qrow + ks * 32 + lg * 8);
            PIN8(qfr[qf][ks]);
        }
    }

    f32x4 acco[2][8] = {};

    for (int kt = 0; kt < nkt; ++kt) {
        const int cur = kt & 1;
        char* sK = smem + cur * 32768;
        char* sV = smem + 65536 + cur * 32768;
        char* sP = smem + 131072;

        WAIT_VM0();                  // this wave's staging of tile kt done
        BARRIER();                   // all waves' slices done
        __builtin_amdgcn_sched_barrier(0);

        if (kt + 1 < nkt) {
            char* nK = smem + (cur ^ 1) * 32768;
            char* nV = smem + 65536 + (cur ^ 1) * 32768;
#pragma unroll
            for (int i = 0; i < 4; ++i) {
                gll16(srcK[i], nK + (size_t)(w * 256 + i * 64) * 16);
                gll16(srcV[i], nV + (size_t)(w * 256 + i * 64) * 16);
                srcK[i] += 64 * 256;
                srcV[i] += 64;
            }
        }

        // ---- S phase: 32q x 32k (own k-half) ----
        f32x4 sacc[2][2] = {};       // [qf][kf]
        __builtin_amdgcn_s_setprio(1);
#pragma unroll
        for (int ks = 0; ks < 8; ++ks) {
            int coff = (ks * 32 + lg * 8) * 2;
#pragma unroll
            for (int kf = 0; kf < 2; ++kf) {
                int krow = wkh * 32 + kf * 16 + lr;
                int off = (krow * 512 + coff) ^ ((krow & 7) << 4);
                short8 kb = *reinterpret_cast<const short8*>(sK + off);
                sacc[0][kf] = mfma16(qfr[0][ks], kb, sacc[0][kf]);
                sacc[1][kf] = mfma16(qfr[1][ks], kb, sacc[1][kf]);
            }
        }
        __builtin_amdgcn_s_setprio(0);

        // ---- P = exp(S*SCALE) -> LDS bf16 (swizzled) ----
#pragma unroll
        for (int qf = 0; qf < 2; ++qf)
#pragma unroll
            for (int kf = 0; kf < 2; ++kf)
#pragma unroll
                for (int r = 0; r < 4; ++r) {
                    float p = __expf(sacc[qf][kf][r] * SCALE);
                    int q = q0 + qf * 16 + lg * 4 + r;
                    int kcol = wkh * 32 + kf * 16 + lr;
                    int off = (q * 128 + kcol * 2) ^ ((q & 7) << 4);
                    *reinterpret_cast<unsigned short*>(sP + off) = f2bf(p);
                }

        WAIT_LGKM0();                // P writes drained
        BARRIER();
        __builtin_amdgcn_sched_barrier(0);

        // ---- PV phase: 32q x 128d (own d-half) over 64 k ----
        __builtin_amdgcn_s_setprio(1);
#pragma unroll
        for (int kk = 0; kk < 2; ++kk) {
            int coff = (kk * 32 + lg * 8) * 2;
            short8 pa[2];
#pragma unroll
            for (int qf = 0; qf < 2; ++qf) {
                int qq = q0 + qf * 16 + lr;
                int offa = (qq * 128 + coff) ^ ((qq & 7) << 4);
                pa[qf] = *reinterpret_cast<const short8*>(sP + offa);
            }
#pragma unroll
            for (int df = 0; df < 8; ++df) {
                int d = wds * 128 + df * 16 + lr;
                int offb = (d * 128 + coff) ^ ((d & 7) << 4);
                short8 vb = *reinterpret_cast<const short8*>(sV + offb);
                acco[0][df] = mfma16(pa[0], vb, acco[0][df]);
                acco[1][df] = mfma16(pa[1], vb, acco[1][df]);
            }
        }
        __builtin_amdgcn_s_setprio(0);
    }

    // epilogue: f32 store to out (kh=0) or partial buffer (kh=1)
    float* dst = (kh == 0) ? out : part;
#pragma unroll
    for (int qf = 0; qf < 2; ++qf)
#pragma unroll
        for (int df = 0; df < 8; ++df) {
            int d = wds * 128 + df * 16 + lr;
            int q0r = qbase + q0 + qf * 16 + lg * 4;
#pragma unroll
            for (int r = 0; r < 4; ++r)
                dst[(size_t)(b * N_ + q0r + r) * 256 + d] = acco[qf][df][r];
        }
}

// out += part  (4.2M f32)
__global__ __launch_bounds__(256) void k_add(
    float* __restrict__ out, const float* __restrict__ part)
{
    int t = blockIdx.x * 256 + threadIdx.x;
#pragma unroll
    for (int i = 0; i < 4; ++i) {
        int idx = t + i * 262144;
        float4 a = reinterpret_cast<float4*>(out)[idx];
        float4 p = reinterpret_cast<const float4*>(part)[idx];
        a.x += p.x; a.y += p.y; a.z += p.z; a.w += p.w;
        reinterpret_cast<float4*>(out)[idx] = a;
    }
}

extern "C" void kernel_launch(void* const* d_in, const int* in_sizes, int n_in,
                              void* d_out, int out_size, void* d_ws, size_t ws_size,
                              hipStream_t stream)
{
    const float* x  = (const float*)d_in[0];
    const float* Wq = (const float*)d_in[1];
    const float* Wk = (const float*)d_in[2];
    const float* Wv = (const float*)d_in[3];

    char* ws = (char*)d_ws;
    unsigned short* Qb = (unsigned short*)(ws);              //  8 MB
    unsigned short* Kb = (unsigned short*)(ws + 8388608);    //  8 MB
    unsigned short* Vt = (unsigned short*)(ws + 16777216);   //  8 MB
    unsigned short* Wb = (unsigned short*)(ws + 25165824);   // 384 KB
    float* part1       = (float*)(ws + 25559040);            //  16 MB
    float* out = (float*)d_out;

    k_cvtw<<<dim3(96), dim3(256), 0, stream>>>(Wq, Wk, Wv, Wb);

    hipFuncSetAttribute((const void*)k_proj,
                        hipFuncAttributeMaxDynamicSharedMemorySize, 98304);
    k_proj<<<dim3(256), dim3(512), 98304, stream>>>(x, Wb, Qb, Kb, Vt);

    hipFuncSetAttribute((const void*)k_zv,
                        hipFuncAttributeMaxDynamicSharedMemorySize, 131072);
    k_zv<<<dim3(128, 2), dim3(512), 131072, stream>>>(Qb, Kb, Vt);

    hipFuncSetAttribute((const void*)k_attn,
                        hipFuncAttributeMaxDynamicSharedMemorySize, 147456);
    if (ws_size >= (size_t)25559040 + 16777216) {
        k_attn<<<dim3(64, 2, 2), dim3(512), 147456, stream>>>(
            Qb, Kb, Vt, out, part1, 64);
        k_add<<<dim3(1024), dim3(256), 0, stream>>>(out, part1);
    } else {
        k_attn<<<dim3(64, 1, 2), dim3(512), 147456, stream>>>(
            Qb, Kb, Vt, out, out, 128);
    }
}

// Round 18
// 251.707 us; speedup vs baseline: 1.7855x; 1.0084x over previous
//
#include <hip/hip_runtime.h>
#include <hip/hip_bf16.h>

// Attention with softmax over the QUERY axis (axis=1):
//   attn[:,q,k] = exp(S[q,k]) / Z[k],  Z[k] = sum_q exp(S[q,k])
//   out = expS @ (diag(1/Z) V)   -- 1/Z folded into V by k_zv's epilogue.
// B=2, N=8192, D=256. All matmuls via mfma_f32_16x16x32_bf16.
// R18: REVERT to proven R15 (253.8us, absmax 4.9e-4). The R16/R17 32x32
// P-in-register branch failed correctness twice with an unlocatable
// fine-grained error despite matching the HK-verified routing recipe --
// falsified for blind development. Banking the best-known state.

#define N_ 8192
#define SCALE 0.0625f

typedef __attribute__((ext_vector_type(8))) short short8;
typedef __attribute__((ext_vector_type(4))) float f32x4;
typedef __attribute__((ext_vector_type(4))) unsigned short ushort4_t;

__device__ inline unsigned short f2bf(float f) {
    unsigned int x = __float_as_uint(f);
    unsigned int r = (x + 0x7fffu + ((x >> 16) & 1u)) >> 16;  // RNE
    return (unsigned short)r;
}

__device__ inline short8 ldg8(const unsigned short* p) {
    return *reinterpret_cast<const short8*>(p);
}

__device__ inline short8 cvt8(const float* p) {
    float4 a = *(const float4*)p;
    float4 b = *(const float4*)(p + 4);
    short8 r;
    r[0] = (short)f2bf(a.x); r[1] = (short)f2bf(a.y);
    r[2] = (short)f2bf(a.z); r[3] = (short)f2bf(a.w);
    r[4] = (short)f2bf(b.x); r[5] = (short)f2bf(b.y);
    r[6] = (short)f2bf(b.z); r[7] = (short)f2bf(b.w);
    return r;
}

__device__ inline f32x4 mfma16(short8 a, short8 b, f32x4 c) {
    return __builtin_amdgcn_mfma_f32_16x16x32_bf16(a, b, c, 0, 0, 0);
}

__device__ inline float bf2f(unsigned short u) {
    return __uint_as_float(((unsigned)u) << 16);
}

#define PIN8(v) asm volatile("" : "+v"(v))

typedef __attribute__((address_space(3))) unsigned int lds_u32;
typedef __attribute__((address_space(1))) const unsigned int glb_u32;
__device__ __forceinline__ void gll16(const void* g, void* l) {
    __builtin_amdgcn_global_load_lds((glb_u32*)g, (lds_u32*)l, 16, 0, 0);
}
#define WAIT_VM0()   asm volatile("s_waitcnt vmcnt(0)" ::: "memory")
#define WAIT_LGKM0() asm volatile("s_waitcnt lgkmcnt(0)" ::: "memory")
#define BARRIER()    __builtin_amdgcn_s_barrier()

// ---------------------------------------------------------------------------
// Kernel 0: W (3 x 256x256 f32) -> Wb (768x256 bf16), concatenated Q|K|V.
// ---------------------------------------------------------------------------
__global__ __launch_bounds__(256) void k_cvtw(
    const float* __restrict__ Wq, const float* __restrict__ Wk,
    const float* __restrict__ Wv, unsigned short* __restrict__ Wb)
{
    int t = blockIdx.x * 256 + threadIdx.x;
    int e8 = t * 8;
    const float* src = (e8 < 65536) ? Wq + e8
                     : (e8 < 131072) ? Wk + (e8 - 65536)
                                     : Wv + (e8 - 131072);
    *reinterpret_cast<short8*>(Wb + e8) = cvt8(src);
}

// ---------------------------------------------------------------------------
// Kernel 1 (v3): QKV projection (proven R14).
// ---------------------------------------------------------------------------
__global__ __launch_bounds__(512, 1) void k_proj(
    const float* __restrict__ x, const unsigned short* __restrict__ Wb,
    unsigned short* __restrict__ Qb, unsigned short* __restrict__ Kb,
    unsigned short* __restrict__ Vt)
{
    extern __shared__ char smem[];
    unsigned short* sX = (unsigned short*)smem;        // 32 KB
    char* sW = smem + 32768;                           // 2 x 32 KB
    const int rb = blockIdx.x;
    const int tid = threadIdx.x, w = tid >> 6, lane = tid & 63;
    const int lr = lane & 15, lg = lane >> 4;
    const int wqs = w >> 2, wes = w & 3;

    int eoff[4], doff[4];
#pragma unroll
    for (int i = 0; i < 4; ++i) {
        int L = tid + i * 512;
        int r = L >> 5, c = (L & 31) ^ (r & 7);
        eoff[i] = r * 256 + c * 8;
        doff[i] = L * 16;
    }

    const unsigned short* wsrc = Wb;
#pragma unroll
    for (int i = 0; i < 4; ++i)
        gll16(wsrc + eoff[i], sW + doff[i]);

#pragma unroll
    for (int i = 0; i < 4; ++i) {
        int g = tid + i * 512;
        int r = g >> 5, c = g & 31;
        int off = (r * 512 + c * 16) ^ ((r & 7) << 4);
        *reinterpret_cast<short8*>(reinterpret_cast<char*>(sX) + off) =
            cvt8(x + (size_t)(rb * 64 + r) * 256 + c * 8);
    }
    __syncthreads();

    short8 xf[2][8];
#pragma unroll
    for (int qf = 0; qf < 2; ++qf)
#pragma unroll
        for (int ks = 0; ks < 8; ++ks) {
            int row = wqs * 32 + qf * 16 + lr;
            int off = (row * 512 + (ks * 32 + lg * 8) * 2) ^ ((row & 7) << 4);
            xf[qf][ks] = *reinterpret_cast<const short8*>(
                reinterpret_cast<const char*>(sX) + off);
            PIN8(xf[qf][ks]);
        }

    for (int c = 0; c < 12; ++c) {
        const int cur = c & 1;
        const char* sWc = sW + cur * 32768;

        WAIT_VM0();
        BARRIER();
        __builtin_amdgcn_sched_barrier(0);

        if (c + 1 < 12) {
            const unsigned short* wn = Wb + (size_t)(c + 1) * 64 * 256;
            char* nW = sW + (cur ^ 1) * 32768;
#pragma unroll
            for (int i = 0; i < 4; ++i)
                gll16(wn + eoff[i], nW + doff[i]);
        }

        f32x4 acc[2] = {};
#pragma unroll
        for (int ks = 0; ks < 8; ++ks) {
            int row = wes * 16 + lr;
            int off = (row * 512 + (ks * 32 + lg * 8) * 2) ^ ((row & 7) << 4);
            short8 wf = *reinterpret_cast<const short8*>(sWc + off);
            acc[0] = mfma16(xf[0][ks], wf, acc[0]);
            acc[1] = mfma16(xf[1][ks], wf, acc[1]);
        }

        int mat = c >> 2;
        int ecol = (c & 3) * 64 + wes * 16 + lr;
#pragma unroll
        for (int qf = 0; qf < 2; ++qf) {
            int rbase = rb * 64 + wqs * 32 + qf * 16 + lg * 4;
            if (mat < 2) {
                unsigned short* dst = (mat == 0) ? Qb : Kb;
#pragma unroll
                for (int r = 0; r < 4; ++r)
                    dst[(size_t)(rbase + r) * 256 + ecol] = f2bf(acc[qf][r]);
            } else {
                int bidx = rbase >> 13, nr = rbase & 8191;
                ushort4_t v;
#pragma unroll
                for (int r = 0; r < 4; ++r) v[r] = f2bf(acc[qf][r]);
                *reinterpret_cast<ushort4_t*>(
                    Vt + ((size_t)bidx * 256 + ecol) * 8192 + nr) = v;
            }
        }
    }
}

// ---------------------------------------------------------------------------
// Kernel 2 (k_zv): per (kt,b): Z[k] = sum_q exp(S[q,k]*SCALE), then
// Vt[b][:, kt*64..+64] *= 1/Z in place. (Proven R10, ~55us.)
// ---------------------------------------------------------------------------
__global__ __launch_bounds__(512, 1) void k_zv(
    const unsigned short* __restrict__ Qb, const unsigned short* __restrict__ Kb,
    unsigned short* __restrict__ Vt)
{
    extern __shared__ char smem[];            // Q dbuf: 2 x 65536 B
    __shared__ float zred[8][32];
    __shared__ float zfin[64];
    const int kt = blockIdx.x, b = blockIdx.y;
    const int tid = threadIdx.x, w = tid >> 6, lane = tid & 63;
    const int lr = lane & 15, lg = lane >> 4;
    const int qs = w & 3, kh = w >> 2;

    short8 kfr[2][8];
#pragma unroll
    for (int kn = 0; kn < 2; ++kn)
#pragma unroll
        for (int ks = 0; ks < 8; ++ks) {
            kfr[kn][ks] = ldg8(
                Kb + (size_t)(b * N_ + kt * 64 + kh * 32 + kn * 16 + lr) * 256
                   + ks * 32 + lg * 8);
            PIN8(kfr[kn][ks]);
        }

    int eoff[8], doff[8];
#pragma unroll
    for (int i = 0; i < 8; ++i) {
        int L = i * 512 + w * 64 + lane;
        int r = L >> 5, c = (L & 31) ^ (r & 7);
        eoff[i] = r * 256 + c * 8;
        doff[i] = L * 16;
    }
    const unsigned short* qbase = Qb + (size_t)b * N_ * 256;

#pragma unroll
    for (int i = 0; i < 8; ++i)
        gll16(qbase + eoff[i], smem + doff[i]);

    float zs0 = 0.f, zs1 = 0.f;
    for (int it = 0; it < 64; ++it) {
        const int cur = it & 1;
        const char* sQ = smem + cur * 65536;

        WAIT_VM0();
        BARRIER();
        __builtin_amdgcn_sched_barrier(0);

        if (it + 1 < 64) {
            const unsigned short* qsrc = qbase + (size_t)(it + 1) * 128 * 256;
            char* nQ = smem + (cur ^ 1) * 65536;
#pragma unroll
            for (int i = 0; i < 8; ++i)
                gll16(qsrc + eoff[i], nQ + doff[i]);
        }

        f32x4 acc[2][2] = {};
        __builtin_amdgcn_s_setprio(1);
#pragma unroll
        for (int ks = 0; ks < 8; ++ks) {
            int coff = (ks * 32 + lg * 8) * 2;
#pragma unroll
            for (int qf = 0; qf < 2; ++qf) {
                int row = qs * 32 + qf * 16 + lr;
                int off = (row * 512 + coff) ^ ((row & 7) << 4);
                short8 qa = *reinterpret_cast<const short8*>(sQ + off);
                acc[qf][0] = mfma16(qa, kfr[0][ks], acc[qf][0]);
                acc[qf][1] = mfma16(qa, kfr[1][ks], acc[qf][1]);
            }
        }
        __builtin_amdgcn_s_setprio(0);

#pragma unroll
        for (int qf = 0; qf < 2; ++qf)
#pragma unroll
            for (int r = 0; r < 4; ++r) {
                zs0 += __expf(acc[qf][0][r] * SCALE);
                zs1 += __expf(acc[qf][1][r] * SCALE);
            }
    }

    zs0 += __shfl_xor(zs0, 16); zs0 += __shfl_xor(zs0, 32);
    zs1 += __shfl_xor(zs1, 16); zs1 += __shfl_xor(zs1, 32);
    if (lg == 0) {
        zred[w][lr]      = zs0;
        zred[w][16 + lr] = zs1;
    }
    __syncthreads();
    if (tid < 64) {
        int kh2 = tid >> 5, kc = tid & 31;
        float z = zred[kh2 * 4 + 0][kc] + zred[kh2 * 4 + 1][kc] +
                  zred[kh2 * 4 + 2][kc] + zred[kh2 * 4 + 3][kc];
        zfin[tid] = 1.0f / z;
    }
    __syncthreads();

#pragma unroll
    for (int i = 0; i < 4; ++i) {
        int G = i * 512 + tid;
        int d = G >> 3, c = G & 7;
        unsigned short* p =
            Vt + ((size_t)b * 256 + d) * 8192 + kt * 64 + c * 8;
        short8 v = *reinterpret_cast<short8*>(p);
        short8 o;
#pragma unroll
        for (int j = 0; j < 8; ++j)
            o[j] = (short)f2bf(bf2f((unsigned short)v[j]) * zfin[c * 8 + j]);
        *reinterpret_cast<short8*>(p) = o;
    }
}

// ---------------------------------------------------------------------------
// Kernel 3 (v15): out[q,d] = sum_k exp(S[q,k]*SCALE) * V'[k,d].
// Grid (64 qt, NKH, 2 b), 512 thr (8 waves). qtile 128, BK 64, nkt tiles/blk.
// Waves: wqs=w>>1 (4 strips of 32q); wkh=w&1 (S k-half, 32k);
//        wds=w&1 (PV d-half, 128d). Per wave: S 32q x 32k (sacc[2][2]),
// PV 32q x 128d (acco[2][8], AGPR). qfr 64 VGPR. 2-barrier template.
// LDS: K dbuf 2x32K @0, V dbuf 2x32K @65536, P 16K @131072 = 144 KB.
// ---------------------------------------------------------------------------
__global__ __launch_bounds__(512, 1) void k_attn(
    const unsigned short* __restrict__ Qb, const unsigned short* __restrict__ Kb,
    const unsigned short* __restrict__ Vt, float* __restrict__ out,
    float* __restrict__ part, int nkt)
{
    extern __shared__ char smem[];
    const int qt = blockIdx.x, kh = blockIdx.y, b = blockIdx.z;
    const int tid = threadIdx.x, w = tid >> 6, lane = tid & 63;
    const int lr = lane & 15, lg = lane >> 4;
    const int qbase = qt * 128;
    const int wqs = w >> 1;          // q strip (32 q)
    const int wkh = w & 1;           // S k-half (32 k)
    const int wds = w & 1;           // PV d-half (128 d)
    const int q0 = wqs * 32;
    const int k0 = kh * nkt * 64;

    const unsigned short* srcK[4];
    const unsigned short* srcV[4];
#pragma unroll
    for (int i = 0; i < 4; ++i) {
        int L = w * 256 + i * 64 + lane;
        int r = L >> 5, c = (L & 31) ^ (r & 7);
        srcK[i] = Kb + (size_t)(b * N_ + k0 + r) * 256 + c * 8;
        int d = L >> 3, c2 = (L & 7) ^ (d & 7);
        srcV[i] = Vt + ((size_t)b * 256 + d) * 8192 + k0 + c2 * 8;
    }

    // prologue: stage tile 0 into buffer 0 (async)
#pragma unroll
    for (int i = 0; i < 4; ++i) {
        gll16(srcK[i], smem + (size_t)(w * 256 + i * 64) * 16);
        gll16(srcV[i], smem + 65536 + (size_t)(w * 256 + i * 64) * 16);
        srcK[i] += 64 * 256;
        srcV[i] += 64;
    }

    // hoist Q fragments: 32 rows (2 frags) x 8 d-slices, PINNED (64 VGPR)
    short8 qfr[2][8];
#pragma unroll
    for (int qf = 0; qf < 2; ++qf) {
        const unsigned short* qrow =
            Qb + (size_t)(b * N_ + qbase + q0 + qf * 16 + lr) * 256;
#pragma unroll
        for (int ks = 0; ks < 8; ++ks) {
            qfr[qf][ks] = ldg8(qrow + ks * 32 + lg * 8);
            PIN8(qfr[qf][ks]);
        }
    }

    f32x4 acco[2][8] = {};

    for (int kt = 0; kt < nkt; ++kt) {
        const int cur = kt & 1;
        char* sK = smem + cur * 32768;
        char* sV = smem + 65536 + cur * 32768;
        char* sP = smem + 131072;

        WAIT_VM0();                  // this wave's staging of tile kt done
        BARRIER();                   // all waves' slices done
        __builtin_amdgcn_sched_barrier(0);

        if (kt + 1 < nkt) {
            char* nK = smem + (cur ^ 1) * 32768;
            char* nV = smem + 65536 + (cur ^ 1) * 32768;
#pragma unroll
            for (int i = 0; i < 4; ++i) {
                gll16(srcK[i], nK + (size_t)(w * 256 + i * 64) * 16);
                gll16(srcV[i], nV + (size_t)(w * 256 + i * 64) * 16);
                srcK[i] += 64 * 256;
                srcV[i] += 64;
            }
        }

        // ---- S phase: 32q x 32k (own k-half) ----
        f32x4 sacc[2][2] = {};       // [qf][kf]
        __builtin_amdgcn_s_setprio(1);
#pragma unroll
        for (int ks = 0; ks < 8; ++ks) {
            int coff = (ks * 32 + lg * 8) * 2;
#pragma unroll
            for (int kf = 0; kf < 2; ++kf) {
                int krow = wkh * 32 + kf * 16 + lr;
                int off = (krow * 512 + coff) ^ ((krow & 7) << 4);
                short8 kb = *reinterpret_cast<const short8*>(sK + off);
                sacc[0][kf] = mfma16(qfr[0][ks], kb, sacc[0][kf]);
                sacc[1][kf] = mfma16(qfr[1][ks], kb, sacc[1][kf]);
            }
        }
        __builtin_amdgcn_s_setprio(0);

        // ---- P = exp(S*SCALE) -> LDS bf16 (swizzled) ----
#pragma unroll
        for (int qf = 0; qf < 2; ++qf)
#pragma unroll
            for (int kf = 0; kf < 2; ++kf)
#pragma unroll
                for (int r = 0; r < 4; ++r) {
                    float p = __expf(sacc[qf][kf][r] * SCALE);
                    int q = q0 + qf * 16 + lg * 4 + r;
                    int kcol = wkh * 32 + kf * 16 + lr;
                    int off = (q * 128 + kcol * 2) ^ ((q & 7) << 4);
                    *reinterpret_cast<unsigned short*>(sP + off) = f2bf(p);
                }

        WAIT_LGKM0();                // P writes drained
        BARRIER();
        __builtin_amdgcn_sched_barrier(0);

        // ---- PV phase: 32q x 128d (own d-half) over 64 k ----
        __builtin_amdgcn_s_setprio(1);
#pragma unroll
        for (int kk = 0; kk < 2; ++kk) {
            int coff = (kk * 32 + lg * 8) * 2;
            short8 pa[2];
#pragma unroll
            for (int qf = 0; qf < 2; ++qf) {
                int qq = q0 + qf * 16 + lr;
                int offa = (qq * 128 + coff) ^ ((qq & 7) << 4);
                pa[qf] = *reinterpret_cast<const short8*>(sP + offa);
            }
#pragma unroll
            for (int df = 0; df < 8; ++df) {
                int d = wds * 128 + df * 16 + lr;
                int offb = (d * 128 + coff) ^ ((d & 7) << 4);
                short8 vb = *reinterpret_cast<const short8*>(sV + offb);
                acco[0][df] = mfma16(pa[0], vb, acco[0][df]);
                acco[1][df] = mfma16(pa[1], vb, acco[1][df]);
            }
        }
        __builtin_amdgcn_s_setprio(0);
    }

    // epilogue: f32 store to out (kh=0) or partial buffer (kh=1)
    float* dst = (kh == 0) ? out : part;
#pragma unroll
    for (int qf = 0; qf < 2; ++qf)
#pragma unroll
        for (int df = 0; df < 8; ++df) {
            int d = wds * 128 + df * 16 + lr;
            int q0r = qbase + q0 + qf * 16 + lg * 4;
#pragma unroll
            for (int r = 0; r < 4; ++r)
                dst[(size_t)(b * N_ + q0r + r) * 256 + d] = acco[qf][df][r];
        }
}

// out += part  (4.2M f32)
__global__ __launch_bounds__(256) void k_add(
    float* __restrict__ out, const float* __restrict__ part)
{
    int t = blockIdx.x * 256 + threadIdx.x;
#pragma unroll
    for (int i = 0; i < 4; ++i) {
        int idx = t + i * 262144;
        float4 a = reinterpret_cast<float4*>(out)[idx];
        float4 p = reinterpret_cast<const float4*>(part)[idx];
        a.x += p.x; a.y += p.y; a.z += p.z; a.w += p.w;
        reinterpret_cast<float4*>(out)[idx] = a;
    }
}

extern "C" void kernel_launch(void* const* d_in, const int* in_sizes, int n_in,
                              void* d_out, int out_size, void* d_ws, size_t ws_size,
                              hipStream_t stream)
{
    const float* x  = (const float*)d_in[0];
    const float* Wq = (const float*)d_in[1];
    const float* Wk = (const float*)d_in[2];
    const float* Wv = (const float*)d_in[3];

    char* ws = (char*)d_ws;
    unsigned short* Qb = (unsigned short*)(ws);              //  8 MB
    unsigned short* Kb = (unsigned short*)(ws + 8388608);    //  8 MB
    unsigned short* Vt = (unsigned short*)(ws + 16777216);   //  8 MB
    unsigned short* Wb = (unsigned short*)(ws + 25165824);   // 384 KB
    float* part1       = (float*)(ws + 25559040);            //  16 MB
    float* out = (float*)d_out;

    k_cvtw<<<dim3(96), dim3(256), 0, stream>>>(Wq, Wk, Wv, Wb);

    hipFuncSetAttribute((const void*)k_proj,
                        hipFuncAttributeMaxDynamicSharedMemorySize, 98304);
    k_proj<<<dim3(256), dim3(512), 98304, stream>>>(x, Wb, Qb, Kb, Vt);

    hipFuncSetAttribute((const void*)k_zv,
                        hipFuncAttributeMaxDynamicSharedMemorySize, 131072);
    k_zv<<<dim3(128, 2), dim3(512), 131072, stream>>>(Qb, Kb, Vt);

    hipFuncSetAttribute((const void*)k_attn,
                        hipFuncAttributeMaxDynamicSharedMemorySize, 147456);
    if (ws_size >= (size_t)25559040 + 16777216) {
        k_attn<<<dim3(64, 2, 2), dim3(512), 147456, stream>>>(
            Qb, Kb, Vt, out, part1, 64);
        k_add<<<dim3(1024), dim3(256), 0, stream>>>(out, part1);
    } else {
        k_attn<<<dim3(64, 1, 2), dim3(512), 147456, stream>>>(
            Qb, Kb, Vt, out, out, 128);
    }
}